// Round 7
// baseline (4857.663 us; speedup 1.0000x reference)
//
#include <hip/hip_runtime.h>
#include <hip/hip_bf16.h>

#define BQ 2
#define TT 2048
#define DD 512
#define HH 8
#define LL 4
#define DFFN 2048
#define WWIN 256
#define DHD 64
#define MM (BQ*TT)   // 4096 token rows
#define NOUT (MM*DD)

// ---------- diagnostic fill (fp32) ----------
__global__ __launch_bounds__(256) void fill_const(float* __restrict__ out, float C, int n) {
  int i = blockIdx.x * 256 + threadIdx.x;
  if (i < n) out[i] = C;
}

// ---------- tokens (fp32) -> fp32 residual x ----------
__global__ __launch_bounds__(256) void copy_f32(const float* __restrict__ in,
                                                float* __restrict__ out, int n) {
  int i = blockIdx.x * 256 + threadIdx.x;
  if (i < n) out[i] = in[i];
}

// ---------- LayerNorm: fp32 x -> bf16 out (intermediate) ----------
__global__ __launch_bounds__(256) void ln_kernel(const float* __restrict__ x,
                                                 const float* __restrict__ g,
                                                 const float* __restrict__ b,
                                                 __hip_bfloat16* __restrict__ out) {
  const int wave = threadIdx.x >> 6, lane = threadIdx.x & 63;
  const int row = blockIdx.x * 4 + wave;
  const float* xr = x + (size_t)row * DD;
  float v[8];
  float s = 0.f;
#pragma unroll
  for (int i = 0; i < 8; ++i) { v[i] = xr[lane + i * 64]; s += v[i]; }
#pragma unroll
  for (int off = 32; off; off >>= 1) s += __shfl_xor(s, off);
  float mu = s * (1.f / DD);
  float qs = 0.f;
#pragma unroll
  for (int i = 0; i < 8; ++i) { float d = v[i] - mu; qs += d * d; }
#pragma unroll
  for (int off = 32; off; off >>= 1) qs += __shfl_xor(qs, off);
  float rstd = rsqrtf(qs * (1.f / DD) + 1e-5f);
#pragma unroll
  for (int i = 0; i < 8; ++i) {
    int c = lane + i * 64;
    out[(size_t)row * DD + c] = __float2bfloat16((v[i] - mu) * rstd * g[c] + b[c]);
  }
}

// ---------- final LayerNorm: fp32 x -> FP32 out (the fix) ----------
__global__ __launch_bounds__(256) void ln_f32out(const float* __restrict__ x,
                                                 const float* __restrict__ g,
                                                 const float* __restrict__ b,
                                                 float* __restrict__ out) {
  const int wave = threadIdx.x >> 6, lane = threadIdx.x & 63;
  const int row = blockIdx.x * 4 + wave;
  const float* xr = x + (size_t)row * DD;
  float v[8];
  float s = 0.f;
#pragma unroll
  for (int i = 0; i < 8; ++i) { v[i] = xr[lane + i * 64]; s += v[i]; }
#pragma unroll
  for (int off = 32; off; off >>= 1) s += __shfl_xor(s, off);
  float mu = s * (1.f / DD);
  float qs = 0.f;
#pragma unroll
  for (int i = 0; i < 8; ++i) { float d = v[i] - mu; qs += d * d; }
#pragma unroll
  for (int off = 32; off; off >>= 1) qs += __shfl_xor(qs, off);
  float rstd = rsqrtf(qs * (1.f / DD) + 1e-5f);
#pragma unroll
  for (int i = 0; i < 8; ++i) {
    int c = lane + i * 64;
    out[(size_t)row * DD + c] = (v[i] - mu) * rstd * g[c] + b[c];
  }
}

// ---------- RoPE in-place on q,k sections of qkv (inline trig) ----------
__global__ __launch_bounds__(256) void rope_kernel(__hip_bfloat16* __restrict__ qkv) {
  int idx = blockIdx.x * 256 + threadIdx.x;   // B*T*H*32 = 1,048,576
  int i = idx & 31;
  int h = (idx >> 5) & 7;
  int t = (idx >> 8) & 2047;
  int b = idx >> 19;
  size_t base = ((size_t)(b * TT + t)) * 1536 + h * 64;
  float freq = powf(10000.f, -(float)i * (1.f / 32.f));
  float ang = (float)t * freq;
  float c = cosf(ang), s = sinf(ang);
  float a0 = __bfloat162float(qkv[base + i]);
  float a1 = __bfloat162float(qkv[base + i + 32]);
  qkv[base + i]      = __float2bfloat16(a0 * c - a1 * s);
  qkv[base + i + 32] = __float2bfloat16(a1 * c + a0 * s);
  base += 512;
  a0 = __bfloat162float(qkv[base + i]);
  a1 = __bfloat162float(qkv[base + i + 32]);
  qkv[base + i]      = __float2bfloat16(a0 * c - a1 * s);
  qkv[base + i + 32] = __float2bfloat16(a1 * c + a0 * s);
}

// ---------- NAIVE GEMM: A (M,K) bf16  x  B (K,N) fp32 -> epilogue ----------
enum { EPI_BF16 = 0, EPI_GELU = 1, EPI_ADDF32 = 2 };

template <int EPI>
__global__ __launch_bounds__(256) void gemm_nt(const __hip_bfloat16* __restrict__ A,
                                               const float* __restrict__ B,
                                               const float* __restrict__ bias,
                                               __hip_bfloat16* __restrict__ Obf,
                                               float* __restrict__ Of,
                                               int M, int N, int K,
                                               int ostride, int ooff) {
  __shared__ float As[64][33];
  __shared__ float Bs[32][65];
  const int tx = threadIdx.x & 15;
  const int ty = threadIdx.x >> 4;
  const int m0 = blockIdx.y * 64;
  const int n0 = blockIdx.x * 64;

  float acc[4][4] = {};

  const int ar = threadIdx.x >> 2;
  const int ac = (threadIdx.x & 3) * 8;
  const int bk = threadIdx.x >> 3;
  const int bn = (threadIdx.x & 7) * 8;

  for (int k0 = 0; k0 < K; k0 += 32) {
    __syncthreads();
#pragma unroll
    for (int i = 0; i < 8; ++i) {
      As[ar][ac + i] = __bfloat162float(A[(size_t)(m0 + ar) * K + k0 + ac + i]);
      Bs[bk][bn + i] = B[(size_t)(k0 + bk) * N + n0 + bn + i];
    }
    __syncthreads();
#pragma unroll 8
    for (int kk = 0; kk < 32; ++kk) {
      float a[4], bv[4];
#pragma unroll
      for (int i = 0; i < 4; ++i) a[i]  = As[ty * 4 + i][kk];
#pragma unroll
      for (int j = 0; j < 4; ++j) bv[j] = Bs[kk][tx * 4 + j];
#pragma unroll
      for (int i = 0; i < 4; ++i)
#pragma unroll
        for (int j = 0; j < 4; ++j)
          acc[i][j] += a[i] * bv[j];
    }
  }

#pragma unroll
  for (int i = 0; i < 4; ++i) {
    const int row = m0 + ty * 4 + i;
#pragma unroll
    for (int j = 0; j < 4; ++j) {
      const int col = n0 + tx * 4 + j;
      float v = acc[i][j] + bias[col];
      size_t idx = (size_t)row * ostride + ooff + col;
      if (EPI == EPI_BF16) {
        Obf[idx] = __float2bfloat16(v);
      } else if (EPI == EPI_GELU) {
        float ge = 0.5f * v * (1.f + erff(v * 0.70710678118654752f));
        Obf[idx] = __float2bfloat16(ge);
      } else {
        Of[idx] += v;
      }
    }
  }
}

// ---------- NAIVE attention: one wave per query, lane = head dim ----------
__global__ __launch_bounds__(256) void attn_naive(const __hip_bfloat16* __restrict__ qkv,
                                                  __hip_bfloat16* __restrict__ out) {
  const int wave = threadIdx.x >> 6, lane = threadIdx.x & 63;
  const int bh = blockIdx.y;
  const int b = bh >> 3, h = bh & 7;
  const int qg = blockIdx.x * 4 + wave;

  const size_t rowQ = ((size_t)(b * TT + qg)) * 1536 + h * 64;
  const float qd = __bfloat162float(qkv[rowQ + lane]);

  const int jlo = (qg > (WWIN - 1)) ? (qg - (WWIN - 1)) : 0;

  float m = -1e30f, l = 0.f, acc = 0.f;
  for (int j = jlo; j <= qg; ++j) {
    const size_t rowJ = ((size_t)(b * TT + j)) * 1536 + h * 64;
    float p = qd * __bfloat162float(qkv[rowJ + 512 + lane]);
#pragma unroll
    for (int off = 32; off; off >>= 1) p += __shfl_xor(p, off);
    const float s = p * 0.125f;
    const float mn = fmaxf(m, s);
    const float alpha = expf(m - mn);
    const float e = expf(s - mn);
    const float vd = __bfloat162float(qkv[rowJ + 1024 + lane]);
    l = l * alpha + e;
    acc = acc * alpha + e * vd;
    m = mn;
  }
  out[((size_t)(b * TT + qg)) * 512 + h * 64 + lane] = __float2bfloat16(acc / l);
}

// ---------- host launch ----------
extern "C" void kernel_launch(void* const* d_in, const int* in_sizes, int n_in,
                              void* d_out, int out_size, void* d_ws, size_t ws_size,
                              hipStream_t stream) {
  float* outF = (float*)d_out;   // OUTPUT IS FP32 (reference output dtype)

  // interface tripwires (host-branch, capture-stable)
  int code = 0;
  if (n_in != 19)                      code = 1;
  else if (in_sizes[0]  != 2097152)    code = 2;
  else if (in_sizes[1]  != 1048576)    code = 3;
  else if (in_sizes[9]  != 4194304)    code = 4;
  else if (in_sizes[17] != 512)        code = 5;
  if (code != 0 || ws_size < 29360128ull) {
    float C = code ? (150.f + 15.f * (float)code) : (1000.f + (float)(ws_size >> 20));
    fill_const<<<8192, 256, 0, stream>>>(outF, C, NOUT);
    return;
  }

  const float* tokens = (const float*)d_in[0];
  const float* Wq  = (const float*)d_in[1];   // (L, 512, 512) row-major (K,N)
  const float* Wk  = (const float*)d_in[2];
  const float* Wv  = (const float*)d_in[3];
  const float* Wo  = (const float*)d_in[4];
  const float* bq  = (const float*)d_in[5];
  const float* bk  = (const float*)d_in[6];
  const float* bv  = (const float*)d_in[7];
  const float* bo  = (const float*)d_in[8];
  const float* W1  = (const float*)d_in[9];   // (L, 512, 2048)
  const float* b1  = (const float*)d_in[10];
  const float* W2  = (const float*)d_in[11];  // (L, 2048, 512)
  const float* b2  = (const float*)d_in[12];
  const float* g1  = (const float*)d_in[13];
  const float* be1 = (const float*)d_in[14];
  const float* g2  = (const float*)d_in[15];
  const float* be2 = (const float*)d_in[16];
  const float* gf  = (const float*)d_in[17];
  const float* bf  = (const float*)d_in[18];

  // ws layout — 29,360,128 bytes total
  char* ws = (char*)d_ws;
  float* x              = (float*)(ws + 0);                 //  8,388,608
  __hip_bfloat16* xn    = (__hip_bfloat16*)(ws + 8388608);  //  4,194,304
  __hip_bfloat16* qkv   = (__hip_bfloat16*)(ws + 12582912); // 12,582,912
  __hip_bfloat16* ao    = (__hip_bfloat16*)(ws + 25165824); //  4,194,304
  __hip_bfloat16* hbuf  = (__hip_bfloat16*)(ws + 12582912); // aliases qkv+ao exactly

  copy_f32<<<8192, 256, 0, stream>>>(tokens, x, NOUT);

  for (int l = 0; l < LL; ++l) {
    ln_kernel<<<1024, 256, 0, stream>>>(x, g1 + l * 512, be1 + l * 512, xn);
    gemm_nt<EPI_BF16><<<dim3(8, 64), 256, 0, stream>>>(
        xn, Wq + (size_t)l * 262144, bq + l * 512, qkv, nullptr, MM, 512, 512, 1536, 0);
    gemm_nt<EPI_BF16><<<dim3(8, 64), 256, 0, stream>>>(
        xn, Wk + (size_t)l * 262144, bk + l * 512, qkv, nullptr, MM, 512, 512, 1536, 512);
    gemm_nt<EPI_BF16><<<dim3(8, 64), 256, 0, stream>>>(
        xn, Wv + (size_t)l * 262144, bv + l * 512, qkv, nullptr, MM, 512, 512, 1536, 1024);
    rope_kernel<<<4096, 256, 0, stream>>>(qkv);
    attn_naive<<<dim3(512, 16), 256, 0, stream>>>(qkv, ao);
    gemm_nt<EPI_ADDF32><<<dim3(8, 64), 256, 0, stream>>>(
        ao, Wo + (size_t)l * 262144, bo + l * 512, nullptr, x, MM, 512, 512, 512, 0);
    ln_kernel<<<1024, 256, 0, stream>>>(x, g2 + l * 512, be2 + l * 512, xn);
    gemm_nt<EPI_GELU><<<dim3(32, 64), 256, 0, stream>>>(
        xn, W1 + (size_t)l * 1048576, b1 + l * 2048, hbuf, nullptr, MM, 2048, 512, 2048, 0);
    gemm_nt<EPI_ADDF32><<<dim3(8, 64), 256, 0, stream>>>(
        hbuf, W2 + (size_t)l * 1048576, b2 + l * 512, nullptr, x, MM, 512, 2048, 512, 0);
  }
  ln_f32out<<<1024, 256, 0, stream>>>(x, gf, bf, outF);
}

// Round 8
// 1426.712 us; speedup vs baseline: 3.4048x; 3.4048x over previous
//
#include <hip/hip_runtime.h>
#include <hip/hip_bf16.h>

#define BQ 2
#define TT 2048
#define DD 512
#define HH 8
#define LL 4
#define DFFN 2048
#define WWIN 256
#define DHD 64
#define MM (BQ*TT)   // 4096 token rows
#define NOUT (MM*DD)

typedef __attribute__((ext_vector_type(8))) short bf16x8;
typedef __attribute__((ext_vector_type(4))) float f32x4;

// ---------- helpers ----------
__device__ __forceinline__ float2 bf2_to_f2(unsigned u) {
  union { unsigned v; float f; } a, b;
  a.v = u << 16;
  b.v = u & 0xffff0000u;
  return make_float2(a.f, b.f);
}
__device__ __forceinline__ unsigned pack2bf(float x, float y) {
  __hip_bfloat16 hx = __float2bfloat16(x), hy = __float2bfloat16(y);
  unsigned short ux = *(unsigned short*)&hx, uy = *(unsigned short*)&hy;
  return (unsigned)ux | ((unsigned)uy << 16);
}

// ---------- diagnostic fill ----------
__global__ __launch_bounds__(256) void fill_const(float* __restrict__ out, float C, int n) {
  int i = blockIdx.x * 256 + threadIdx.x;
  if (i < n) out[i] = C;
}

// ---------- tokens -> fp32 residual ----------
__global__ __launch_bounds__(256) void copy_f32(const float* __restrict__ in,
                                                float* __restrict__ out, int n) {
  int i = blockIdx.x * 256 + threadIdx.x;
  if (i < n) out[i] = in[i];
}

// ---------- concat qkv biases (all layers, fp32) ----------
__global__ __launch_bounds__(256) void bqkv_cat(const float* __restrict__ bq,
                                                const float* __restrict__ bk,
                                                const float* __restrict__ bv,
                                                float* __restrict__ o) {
  int idx = blockIdx.x * 256 + threadIdx.x;   // 4*1536
  if (idx >= LL * 1536) return;
  int l = idx / 1536, n = idx % 1536;
  float v;
  if (n < 512)       v = bq[l * 512 + n];
  else if (n < 1024) v = bk[l * 512 + n - 512];
  else               v = bv[l * 512 + n - 1024];
  o[idx] = v;
}

// ---------- weight transpose: fp32 (K,N) -> bf16 (N,K) ----------
__global__ __launch_bounds__(256) void transpose_wb(const float* __restrict__ in,
                                                    __hip_bfloat16* __restrict__ out,
                                                    int K, int N) {
  __shared__ float tile[32][33];
  int n0 = blockIdx.x * 32, k0 = blockIdx.y * 32;
  int tx = threadIdx.x & 31, ty = threadIdx.x >> 5;  // 32 x 8
#pragma unroll
  for (int r = 0; r < 32; r += 8)
    tile[ty + r][tx] = in[(size_t)(k0 + ty + r) * N + n0 + tx];
  __syncthreads();
#pragma unroll
  for (int r = 0; r < 32; r += 8)
    out[(size_t)(n0 + ty + r) * K + k0 + tx] = __float2bfloat16(tile[tx][ty + r]);
}

// ---------- LayerNorm: fp32 -> bf16 ----------
__global__ __launch_bounds__(256) void ln_kernel(const float* __restrict__ x,
                                                 const float* __restrict__ g,
                                                 const float* __restrict__ b,
                                                 __hip_bfloat16* __restrict__ out) {
  const int wave = threadIdx.x >> 6, lane = threadIdx.x & 63;
  const int row = blockIdx.x * 4 + wave;
  const float* xr = x + (size_t)row * DD;
  float v[8];
  float s = 0.f;
#pragma unroll
  for (int i = 0; i < 8; ++i) { v[i] = xr[lane + i * 64]; s += v[i]; }
#pragma unroll
  for (int off = 32; off; off >>= 1) s += __shfl_xor(s, off);
  float mu = s * (1.f / DD);
  float qs = 0.f;
#pragma unroll
  for (int i = 0; i < 8; ++i) { float d = v[i] - mu; qs += d * d; }
#pragma unroll
  for (int off = 32; off; off >>= 1) qs += __shfl_xor(qs, off);
  float rstd = rsqrtf(qs * (1.f / DD) + 1e-5f);
#pragma unroll
  for (int i = 0; i < 8; ++i) {
    int c = lane + i * 64;
    out[(size_t)row * DD + c] = __float2bfloat16((v[i] - mu) * rstd * g[c] + b[c]);
  }
}

// ---------- final LayerNorm: fp32 -> fp32 (in-place safe, row-local) ----------
__global__ __launch_bounds__(256) void ln_f32out(const float* __restrict__ x,
                                                 const float* __restrict__ g,
                                                 const float* __restrict__ b,
                                                 float* __restrict__ out) {
  const int wave = threadIdx.x >> 6, lane = threadIdx.x & 63;
  const int row = blockIdx.x * 4 + wave;
  const float* xr = x + (size_t)row * DD;
  float v[8];
  float s = 0.f;
#pragma unroll
  for (int i = 0; i < 8; ++i) { v[i] = xr[lane + i * 64]; s += v[i]; }
#pragma unroll
  for (int off = 32; off; off >>= 1) s += __shfl_xor(s, off);
  float mu = s * (1.f / DD);
  float qs = 0.f;
#pragma unroll
  for (int i = 0; i < 8; ++i) { float d = v[i] - mu; qs += d * d; }
#pragma unroll
  for (int off = 32; off; off >>= 1) qs += __shfl_xor(qs, off);
  float rstd = rsqrtf(qs * (1.f / DD) + 1e-5f);
#pragma unroll
  for (int i = 0; i < 8; ++i) {
    int c = lane + i * 64;
    out[(size_t)row * DD + c] = (v[i] - mu) * rstd * g[c] + b[c];
  }
}

// ---------- RoPE in-place on q,k sections of qkv ----------
__global__ __launch_bounds__(256) void rope_kernel(__hip_bfloat16* __restrict__ qkv) {
  int idx = blockIdx.x * 256 + threadIdx.x;   // B*T*H*32 = 1,048,576
  int i = idx & 31;
  int h = (idx >> 5) & 7;
  int t = (idx >> 8) & 2047;
  int b = idx >> 19;
  size_t base = ((size_t)(b * TT + t)) * 1536 + h * 64;
  float freq = powf(10000.f, -(float)i * (1.f / 32.f));
  float ang = (float)t * freq;
  float c = cosf(ang), s = sinf(ang);
  float a0 = __bfloat162float(qkv[base + i]);
  float a1 = __bfloat162float(qkv[base + i + 32]);
  qkv[base + i]      = __float2bfloat16(a0 * c - a1 * s);
  qkv[base + i + 32] = __float2bfloat16(a1 * c + a0 * s);
  base += 512;
  a0 = __bfloat162float(qkv[base + i]);
  a1 = __bfloat162float(qkv[base + i + 32]);
  qkv[base + i]      = __float2bfloat16(a0 * c - a1 * s);
  qkv[base + i + 32] = __float2bfloat16(a1 * c + a0 * s);
}

// ---------- MFMA GEMM: A (M,K) bf16 x BT (N,K) bf16 + bias(fp32) ----------
// 128x128 tile, 4 waves as 2x2 of 64x64, 16x16x32 bf16 MFMA.
// C-layout (m89-verified): col = lane&15, row = (lane>>4)*4 + reg.
enum { EPI_BF16 = 0, EPI_GELU = 1, EPI_ADDF32 = 2 };

template <int EPI>
__global__ __launch_bounds__(256, 1) void gemm_bt(const __hip_bfloat16* __restrict__ A,
                                                  const __hip_bfloat16* __restrict__ BT,
                                                  const float* __restrict__ bias,
                                                  __hip_bfloat16* __restrict__ Obf,
                                                  float* __restrict__ Of,
                                                  int M, int N, int K,
                                                  int ostride, int ooff) {
  __shared__ __align__(16) __hip_bfloat16 Ash[128 * 32];
  __shared__ __align__(16) __hip_bfloat16 Bsh[128 * 32];
  const int tid = threadIdx.x;
  const int wave = tid >> 6;
  const int lane = tid & 63;
  const int m0 = blockIdx.y * 128;
  const int n0 = blockIdx.x * 128;
  const int wm = (wave >> 1) * 64;
  const int wn = (wave & 1) * 64;
  const int l15 = lane & 15;
  const int quad = lane >> 4;

  f32x4 acc[4][4] = {};

  const int r0 = tid >> 2;            // rows 0..63
  const int r1 = r0 + 64;             // rows 64..127
  const int o0 = (tid & 3) * 8;       // k-offset (16B chunks)

  const __hip_bfloat16* Ap0 = A + (size_t)(m0 + r0) * K + o0;
  const __hip_bfloat16* Ap1 = A + (size_t)(m0 + r1) * K + o0;
  const __hip_bfloat16* Bp0 = BT + (size_t)(n0 + r0) * K + o0;
  const __hip_bfloat16* Bp1 = BT + (size_t)(n0 + r1) * K + o0;

  for (int k0 = 0; k0 < K; k0 += 32) {
    uint4 a0 = *(const uint4*)(Ap0 + k0);
    uint4 a1 = *(const uint4*)(Ap1 + k0);
    uint4 b0 = *(const uint4*)(Bp0 + k0);
    uint4 b1 = *(const uint4*)(Bp1 + k0);
    __syncthreads();
    *(uint4*)&Ash[r0 * 32 + o0] = a0;
    *(uint4*)&Ash[r1 * 32 + o0] = a1;
    *(uint4*)&Bsh[r0 * 32 + o0] = b0;
    *(uint4*)&Bsh[r1 * 32 + o0] = b1;
    __syncthreads();
    bf16x8 af[4], bfr[4];
#pragma unroll
    for (int i = 0; i < 4; ++i)
      af[i] = *(const bf16x8*)&Ash[(wm + i * 16 + l15) * 32 + quad * 8];
#pragma unroll
    for (int j = 0; j < 4; ++j)
      bfr[j] = *(const bf16x8*)&Bsh[(wn + j * 16 + l15) * 32 + quad * 8];
#pragma unroll
    for (int i = 0; i < 4; ++i)
#pragma unroll
      for (int j = 0; j < 4; ++j)
        acc[i][j] = __builtin_amdgcn_mfma_f32_16x16x32_bf16(af[i], bfr[j], acc[i][j], 0, 0, 0);
  }

#pragma unroll
  for (int j = 0; j < 4; ++j) {
    const int col = n0 + wn + j * 16 + l15;
    const float bv = bias[col];
#pragma unroll
    for (int i = 0; i < 4; ++i) {
      const int row = m0 + wm + i * 16 + quad * 4;
#pragma unroll
      for (int r = 0; r < 4; ++r) {
        float v = acc[i][j][r] + bv;
        size_t idx = (size_t)(row + r) * ostride + ooff + col;
        if (EPI == EPI_BF16) {
          Obf[idx] = __float2bfloat16(v);
        } else if (EPI == EPI_GELU) {
          float ge = 0.5f * v * (1.f + erff(v * 0.70710678118654752f));
          Obf[idx] = __float2bfloat16(ge);
        } else {
          Of[idx] += v;
        }
      }
    }
  }
}

// ---------- LDS-tiled sliding-window attention ----------
// block: 256 threads = (b,h, 16 queries). K window staged in LDS.
__global__ __launch_bounds__(256, 1) void attn_kernel(const __hip_bfloat16* __restrict__ qkv,
                                                      __hip_bfloat16* __restrict__ out) {
  constexpr int KPAD = 72;
  constexpr int SPAD = 273;
  __shared__ __align__(16) __hip_bfloat16 Ksh[272 * KPAD];
  __shared__ __align__(16) float Qsh[16 * 64];
  __shared__ __align__(16) float Ssh[16 * SPAD];
  const int tid = threadIdx.x;
  const int bh = blockIdx.y;
  const int b = bh >> 3, h = bh & 7;
  const int q0 = blockIdx.x * 16;
  const int j0 = (q0 > (WWIN - 1)) ? (q0 - (WWIN - 1)) : 0;
  const int nk = (q0 + 15) - j0 + 1;   // <= 271
  const size_t baseQ = ((size_t)(b * TT + q0)) * 1536 + h * 64;
  const size_t baseK = ((size_t)(b * TT + j0)) * 1536 + 512 + h * 64;
  const size_t baseV = ((size_t)(b * TT + j0)) * 1536 + 1024 + h * 64;

  // stage K window (16B chunks)
  for (int c = tid; c < nk * 8; c += 256) {
    int row = c >> 3, cc = (c & 7) * 8;
    uint4 kv = *(const uint4*)&qkv[baseK + (size_t)row * 1536 + cc];
    *(uint4*)&Ksh[row * KPAD + cc] = kv;
  }
  // stage Q as fp32
  for (int i = tid; i < 16 * 64; i += 256) {
    int q = i >> 6, d = i & 63;
    Qsh[i] = __bfloat162float(qkv[baseQ + (size_t)q * 1536 + d]);
  }
  __syncthreads();

  const int q = tid >> 4;      // 0..15 (16-lane group per query, same wave)
  const int l16 = tid & 15;
  const int qg = q0 + q;

  for (int jt = 0; jt < 17; ++jt) {
    int j = l16 + jt * 16;
    if (j >= nk) break;
    int jj = j0 + j;
    bool ok = (jj <= qg) && ((qg - jj) < WWIN);
    float dot = 0.f;
#pragma unroll
    for (int d8 = 0; d8 < 8; ++d8) {
      uint4 kv = *(const uint4*)&Ksh[j * KPAD + d8 * 8];
      float4 qa = *(const float4*)&Qsh[q * 64 + d8 * 8];
      float4 qb = *(const float4*)&Qsh[q * 64 + d8 * 8 + 4];
      float2 k01 = bf2_to_f2(kv.x), k23 = bf2_to_f2(kv.y);
      float2 k45 = bf2_to_f2(kv.z), k67 = bf2_to_f2(kv.w);
      dot += k01.x * qa.x + k01.y * qa.y + k23.x * qa.z + k23.y * qa.w;
      dot += k45.x * qb.x + k45.y * qb.y + k67.x * qb.z + k67.y * qb.w;
    }
    Ssh[q * SPAD + j] = ok ? dot * 0.125f : -1e30f;
  }

  // softmax within the 16-lane group (same wave, no barrier needed)
  float mloc = -1e30f;
  for (int j = l16; j < nk; j += 16) mloc = fmaxf(mloc, Ssh[q * SPAD + j]);
#pragma unroll
  for (int off = 8; off; off >>= 1) mloc = fmaxf(mloc, __shfl_xor(mloc, off, 16));
  float sloc = 0.f;
  for (int j = l16; j < nk; j += 16) {
    float e = expf(Ssh[q * SPAD + j] - mloc);
    Ssh[q * SPAD + j] = e;
    sloc += e;
  }
#pragma unroll
  for (int off = 8; off; off >>= 1) sloc += __shfl_xor(sloc, off, 16);
  const float inv = 1.f / sloc;

  // PV: thread owns (q, 4 dims)
  const int d4 = l16 * 4;
  float a0 = 0.f, a1 = 0.f, a2 = 0.f, a3 = 0.f;
  for (int j = 0; j < nk; ++j) {
    float p = Ssh[q * SPAD + j];
    uint2 vv = *(const uint2*)&qkv[baseV + (size_t)j * 1536 + d4];
    float2 v01 = bf2_to_f2(vv.x), v23 = bf2_to_f2(vv.y);
    a0 += p * v01.x; a1 += p * v01.y; a2 += p * v23.x; a3 += p * v23.y;
  }
  size_t ob = (size_t)(b * TT + qg) * DD + h * 64 + d4;
  *(uint2*)&out[ob] = make_uint2(pack2bf(a0 * inv, a1 * inv), pack2bf(a2 * inv, a3 * inv));
}

// ---------- host launch ----------
extern "C" void kernel_launch(void* const* d_in, const int* in_sizes, int n_in,
                              void* d_out, int out_size, void* d_ws, size_t ws_size,
                              hipStream_t stream) {
  float* outF = (float*)d_out;   // fp32 output; also serves as the residual x

  int code = 0;
  if (n_in != 19)                      code = 1;
  else if (in_sizes[0]  != 2097152)    code = 2;
  else if (in_sizes[1]  != 1048576)    code = 3;
  else if (in_sizes[9]  != 4194304)    code = 4;
  else if (in_sizes[17] != 512)        code = 5;
  if (code != 0 || ws_size < 23100000ull) {
    float C = code ? (150.f + 15.f * (float)code) : (1000.f + (float)(ws_size >> 20));
    fill_const<<<8192, 256, 0, stream>>>(outF, C, NOUT);
    return;
  }

  const float* tokens = (const float*)d_in[0];
  const float* Wq  = (const float*)d_in[1];   // (L,512,512) (K,N)
  const float* Wk  = (const float*)d_in[2];
  const float* Wv  = (const float*)d_in[3];
  const float* Wo  = (const float*)d_in[4];
  const float* bq  = (const float*)d_in[5];
  const float* bk  = (const float*)d_in[6];
  const float* bv  = (const float*)d_in[7];
  const float* bo  = (const float*)d_in[8];
  const float* W1  = (const float*)d_in[9];   // (L,512,2048)
  const float* b1  = (const float*)d_in[10];
  const float* W2  = (const float*)d_in[11];  // (L,2048,512)
  const float* b2  = (const float*)d_in[12];
  const float* g1  = (const float*)d_in[13];
  const float* be1 = (const float*)d_in[14];
  const float* g2  = (const float*)d_in[15];
  const float* be2 = (const float*)d_in[16];
  const float* gf  = (const float*)d_in[17];
  const float* bf  = (const float*)d_in[18];

  // ws layout — 23,093,248 B total (x lives in d_out)
  char* ws = (char*)d_ws;
  __hip_bfloat16* xn   = (__hip_bfloat16*)(ws + 0);          //  4,194,304
  __hip_bfloat16* qkv  = (__hip_bfloat16*)(ws + 4194304);    // 12,582,912
  __hip_bfloat16* ao   = (__hip_bfloat16*)(ws + 16777216);   //  4,194,304 -> 20,971,520
  __hip_bfloat16* hbuf = (__hip_bfloat16*)(ws + 4194304);    // aliases qkv+ao exactly (16,777,216)
  __hip_bfloat16* wT   = (__hip_bfloat16*)(ws + 20971520);   //  2,097,152 (per-gemm transposed weights)
  float* bqkvc         = (float*)(ws + 23068672);            //  24,576 -> 23,093,248
  float* x             = outF;

  copy_f32<<<8192, 256, 0, stream>>>(tokens, x, NOUT);
  bqkv_cat<<<24, 256, 0, stream>>>(bq, bk, bv, bqkvc);

  for (int l = 0; l < LL; ++l) {
    // LN1 -> xn
    ln_kernel<<<1024, 256, 0, stream>>>(x, g1 + l * 512, be1 + l * 512, xn);
    // Wq|Wk|Wv -> wT (1536,512) bf16
    transpose_wb<<<dim3(16, 16), 256, 0, stream>>>(Wq + (size_t)l * 262144, wT,          512, 512);
    transpose_wb<<<dim3(16, 16), 256, 0, stream>>>(Wk + (size_t)l * 262144, wT + 262144, 512, 512);
    transpose_wb<<<dim3(16, 16), 256, 0, stream>>>(Wv + (size_t)l * 262144, wT + 524288, 512, 512);
    gemm_bt<EPI_BF16><<<dim3(12, 32), 256, 0, stream>>>(
        xn, wT, bqkvc + l * 1536, qkv, nullptr, MM, 1536, 512, 1536, 0);
    rope_kernel<<<4096, 256, 0, stream>>>(qkv);
    attn_kernel<<<dim3(128, 16), 256, 0, stream>>>(qkv, ao);
    // Wo
    transpose_wb<<<dim3(16, 16), 256, 0, stream>>>(Wo + (size_t)l * 262144, wT, 512, 512);
    gemm_bt<EPI_ADDF32><<<dim3(4, 32), 256, 0, stream>>>(
        ao, wT, bo + l * 512, nullptr, x, MM, 512, 512, 512, 0);
    // LN2 -> xn
    ln_kernel<<<1024, 256, 0, stream>>>(x, g2 + l * 512, be2 + l * 512, xn);
    // FFN1 (N=2048)
    transpose_wb<<<dim3(64, 16), 256, 0, stream>>>(W1 + (size_t)l * 1048576, wT, 512, 2048);
    gemm_bt<EPI_GELU><<<dim3(16, 32), 256, 0, stream>>>(
        xn, wT, b1 + l * 2048, hbuf, nullptr, MM, 2048, 512, 2048, 0);
    // FFN2 (K=2048, N=512)
    transpose_wb<<<dim3(16, 64), 256, 0, stream>>>(W2 + (size_t)l * 1048576, wT, 2048, 512);
    gemm_bt<EPI_ADDF32><<<dim3(4, 32), 256, 0, stream>>>(
        hbuf, wT, b2 + l * 512, nullptr, x, MM, 512, 2048, 512, 0);
  }
  ln_f32out<<<1024, 256, 0, stream>>>(x, gf, bf, outF);
}

// Round 9
// 825.152 us; speedup vs baseline: 5.8870x; 1.7290x over previous
//
#include <hip/hip_runtime.h>
#include <hip/hip_bf16.h>

#define BQ 2
#define TT 2048
#define DD 512
#define HH 8
#define LL 4
#define DFFN 2048
#define WWIN 256
#define DHD 64
#define MM (BQ*TT)   // 4096 token rows
#define NOUT (MM*DD)

typedef __attribute__((ext_vector_type(8))) short bf16x8;
typedef __attribute__((ext_vector_type(4))) float f32x4;

// ---------- helpers ----------
__device__ __forceinline__ void lds_load16(const void* g, void* l) {
  __builtin_amdgcn_global_load_lds((const __attribute__((address_space(1))) void*)g,
                                   (__attribute__((address_space(3))) void*)l,
                                   16, 0, 0);
}
__device__ __forceinline__ short bf16bits(float x) {
  __hip_bfloat16 h = __float2bfloat16(x);
  return *(short*)&h;
}

// ---------- diagnostic fill ----------
__global__ __launch_bounds__(256) void fill_const(float* __restrict__ out, float C, int n) {
  int i = blockIdx.x * 256 + threadIdx.x;
  if (i < n) out[i] = C;
}

// ---------- tokens -> fp32 residual ----------
__global__ __launch_bounds__(256) void copy_f32(const float* __restrict__ in,
                                                float* __restrict__ out, int n) {
  int i = blockIdx.x * 256 + threadIdx.x;
  if (i < n) out[i] = in[i];
}

// ---------- concat qkv biases ----------
__global__ __launch_bounds__(256) void bqkv_cat(const float* __restrict__ bq,
                                                const float* __restrict__ bk,
                                                const float* __restrict__ bv,
                                                float* __restrict__ o) {
  int idx = blockIdx.x * 256 + threadIdx.x;
  if (idx >= LL * 1536) return;
  int l = idx / 1536, n = idx % 1536;
  float v;
  if (n < 512)       v = bq[l * 512 + n];
  else if (n < 1024) v = bk[l * 512 + n - 512];
  else               v = bv[l * 512 + n - 1024];
  o[idx] = v;
}

// ---------- weight transpose: fp32 (K,N) -> bf16 (N,K) ----------
__global__ __launch_bounds__(256) void transpose_wb(const float* __restrict__ in,
                                                    __hip_bfloat16* __restrict__ out,
                                                    int K, int N) {
  __shared__ float tile[32][33];
  int n0 = blockIdx.x * 32, k0 = blockIdx.y * 32;
  int tx = threadIdx.x & 31, ty = threadIdx.x >> 5;
#pragma unroll
  for (int r = 0; r < 32; r += 8)
    tile[ty + r][tx] = in[(size_t)(k0 + ty + r) * N + n0 + tx];
  __syncthreads();
#pragma unroll
  for (int r = 0; r < 32; r += 8)
    out[(size_t)(n0 + ty + r) * K + k0 + tx] = __float2bfloat16(tile[tx][ty + r]);
}

// ---------- LayerNorm: fp32 -> bf16 ----------
__global__ __launch_bounds__(256) void ln_kernel(const float* __restrict__ x,
                                                 const float* __restrict__ g,
                                                 const float* __restrict__ b,
                                                 __hip_bfloat16* __restrict__ out) {
  const int wave = threadIdx.x >> 6, lane = threadIdx.x & 63;
  const int row = blockIdx.x * 4 + wave;
  const float* xr = x + (size_t)row * DD;
  float v[8];
  float s = 0.f;
#pragma unroll
  for (int i = 0; i < 8; ++i) { v[i] = xr[lane + i * 64]; s += v[i]; }
#pragma unroll
  for (int off = 32; off; off >>= 1) s += __shfl_xor(s, off);
  float mu = s * (1.f / DD);
  float qs = 0.f;
#pragma unroll
  for (int i = 0; i < 8; ++i) { float d = v[i] - mu; qs += d * d; }
#pragma unroll
  for (int off = 32; off; off >>= 1) qs += __shfl_xor(qs, off);
  float rstd = rsqrtf(qs * (1.f / DD) + 1e-5f);
#pragma unroll
  for (int i = 0; i < 8; ++i) {
    int c = lane + i * 64;
    out[(size_t)row * DD + c] = __float2bfloat16((v[i] - mu) * rstd * g[c] + b[c]);
  }
}

// ---------- final LayerNorm: fp32 -> fp32 ----------
__global__ __launch_bounds__(256) void ln_f32out(const float* __restrict__ x,
                                                 const float* __restrict__ g,
                                                 const float* __restrict__ b,
                                                 float* __restrict__ out) {
  const int wave = threadIdx.x >> 6, lane = threadIdx.x & 63;
  const int row = blockIdx.x * 4 + wave;
  const float* xr = x + (size_t)row * DD;
  float v[8];
  float s = 0.f;
#pragma unroll
  for (int i = 0; i < 8; ++i) { v[i] = xr[lane + i * 64]; s += v[i]; }
#pragma unroll
  for (int off = 32; off; off >>= 1) s += __shfl_xor(s, off);
  float mu = s * (1.f / DD);
  float qs = 0.f;
#pragma unroll
  for (int i = 0; i < 8; ++i) { float d = v[i] - mu; qs += d * d; }
#pragma unroll
  for (int off = 32; off; off >>= 1) qs += __shfl_xor(qs, off);
  float rstd = rsqrtf(qs * (1.f / DD) + 1e-5f);
#pragma unroll
  for (int i = 0; i < 8; ++i) {
    int c = lane + i * 64;
    out[(size_t)row * DD + c] = (v[i] - mu) * rstd * g[c] + b[c];
  }
}

// ---------- RoPE in-place ----------
__global__ __launch_bounds__(256) void rope_kernel(__hip_bfloat16* __restrict__ qkv) {
  int idx = blockIdx.x * 256 + threadIdx.x;
  int i = idx & 31;
  int h = (idx >> 5) & 7;
  int t = (idx >> 8) & 2047;
  int b = idx >> 19;
  size_t base = ((size_t)(b * TT + t)) * 1536 + h * 64;
  float freq = powf(10000.f, -(float)i * (1.f / 32.f));
  float ang = (float)t * freq;
  float c = cosf(ang), s = sinf(ang);
  float a0 = __bfloat162float(qkv[base + i]);
  float a1 = __bfloat162float(qkv[base + i + 32]);
  qkv[base + i]      = __float2bfloat16(a0 * c - a1 * s);
  qkv[base + i + 32] = __float2bfloat16(a1 * c + a0 * s);
  base += 512;
  a0 = __bfloat162float(qkv[base + i]);
  a1 = __bfloat162float(qkv[base + i + 32]);
  qkv[base + i]      = __float2bfloat16(a0 * c - a1 * s);
  qkv[base + i + 32] = __float2bfloat16(a1 * c + a0 * s);
}

// ---------- MFMA GEMM with global_load_lds staging (m97 structure) ----------
enum { EPI_BF16 = 0, EPI_GELU = 1, EPI_ADDF32 = 2 };

template <int EPI>
__global__ __launch_bounds__(256, 1) void gemm_bt(const __hip_bfloat16* __restrict__ A,
                                                  const __hip_bfloat16* __restrict__ BT,
                                                  const float* __restrict__ bias,
                                                  __hip_bfloat16* __restrict__ Obf,
                                                  float* __restrict__ Of,
                                                  int M, int N, int K,
                                                  int ostride, int ooff) {
  __shared__ __align__(16) __hip_bfloat16 Ash[128 * 32];
  __shared__ __align__(16) __hip_bfloat16 Bsh[128 * 32];
  const int tid = threadIdx.x;
  const int wave = tid >> 6;
  const int lane = tid & 63;
  const int m0 = blockIdx.y * 128;
  const int n0 = blockIdx.x * 128;
  const int wm = (wave >> 1) * 64;
  const int wn = (wave & 1) * 64;
  const int l15 = lane & 15;
  const int quad = lane >> 4;

  f32x4 acc[4][4] = {};

  const int r0 = tid >> 2;            // rows 0..63
  const int r1 = r0 + 64;             // rows 64..127
  const int o0 = (tid & 3) * 8;       // k-offset (16B chunks)

  const __hip_bfloat16* Ap0 = A + (size_t)(m0 + r0) * K + o0;
  const __hip_bfloat16* Ap1 = A + (size_t)(m0 + r1) * K + o0;
  const __hip_bfloat16* Bp0 = BT + (size_t)(n0 + r0) * K + o0;
  const __hip_bfloat16* Bp1 = BT + (size_t)(n0 + r1) * K + o0;

  // glds dest: wave-uniform base; HW scatters lane*16B
  __hip_bfloat16* ldsA0 = &Ash[(wave * 64) * 8];
  __hip_bfloat16* ldsA1 = &Ash[(256 + wave * 64) * 8];
  __hip_bfloat16* ldsB0 = &Bsh[(wave * 64) * 8];
  __hip_bfloat16* ldsB1 = &Bsh[(256 + wave * 64) * 8];

  for (int k0 = 0; k0 < K; k0 += 32) {
    __syncthreads();   // prior iter's LDS reads done before overwrite
    lds_load16(Ap0 + k0, ldsA0);
    lds_load16(Ap1 + k0, ldsA1);
    lds_load16(Bp0 + k0, ldsB0);
    lds_load16(Bp1 + k0, ldsB1);
    __syncthreads();   // drains vmcnt: glds data landed
    bf16x8 af[4], bfr[4];
#pragma unroll
    for (int i = 0; i < 4; ++i)
      af[i] = *(const bf16x8*)&Ash[(wm + i * 16 + l15) * 32 + quad * 8];
#pragma unroll
    for (int j = 0; j < 4; ++j)
      bfr[j] = *(const bf16x8*)&Bsh[(wn + j * 16 + l15) * 32 + quad * 8];
#pragma unroll
    for (int i = 0; i < 4; ++i)
#pragma unroll
      for (int j = 0; j < 4; ++j)
        acc[i][j] = __builtin_amdgcn_mfma_f32_16x16x32_bf16(af[i], bfr[j], acc[i][j], 0, 0, 0);
  }

#pragma unroll
  for (int j = 0; j < 4; ++j) {
    const int col = n0 + wn + j * 16 + l15;
    const float bv = bias[col];
#pragma unroll
    for (int i = 0; i < 4; ++i) {
      const int row = m0 + wm + i * 16 + quad * 4;
#pragma unroll
      for (int r = 0; r < 4; ++r) {
        float v = acc[i][j][r] + bv;
        size_t idx = (size_t)(row + r) * ostride + ooff + col;
        if (EPI == EPI_BF16) {
          Obf[idx] = __float2bfloat16(v);
        } else if (EPI == EPI_GELU) {
          float ge = 0.5f * v * (1.f + erff(v * 0.70710678118654752f));
          Obf[idx] = __float2bfloat16(ge);
        } else {
          Of[idx] += v;
        }
      }
    }
  }
}

// ---------- MFMA flash attention ----------
// grid (T/64, B*H), block 256 = 4 waves; wave handles 16 queries (q0+wave*16..+15).
// K window (<=319 rows) staged once in LDS per block; 32-key chunks:
//   S = Q K^T via 16x16x32 MFMA (C: col=key=lane&15, row=q=quad*4+r)
//   online softmax per row (16-lane shfl in quad segments)
//   P -> A-layout via per-wave LDS roundtrip; PV via 4 MFMAs (V B-frags from global)
__global__ __launch_bounds__(256, 1) void attn_mfma(const __hip_bfloat16* __restrict__ qkv,
                                                    __hip_bfloat16* __restrict__ ao) {
  constexpr int KPAD = 72;   // 36 dw stride -> ~2-4-way on b128 frag reads
  constexpr int PPAD = 40;   // P row stride (elems): 20 dw -> 2-way
  __shared__ __align__(16) __hip_bfloat16 Ksh[320 * KPAD];
  __shared__ __align__(16) __hip_bfloat16 Psh[4 * 16 * PPAD];
  const int tid = threadIdx.x;
  const int wave = tid >> 6;
  const int lane = tid & 63;
  const int l15 = lane & 15;
  const int quad = lane >> 4;
  const int bh = blockIdx.y;
  const int b = bh >> 3, h = bh & 7;
  const int q0 = blockIdx.x * 64;
  const int j0 = (q0 > (WWIN - 1)) ? (q0 - (WWIN - 1)) : 0;
  const int nk = (q0 + 63) - j0 + 1;              // <= 319

  const size_t baseK = ((size_t)(b * TT + j0)) * 1536 + 512 + h * 64;
  // stage K window (coalesced uint4)
  for (int c = tid; c < nk * 8; c += 256) {
    int row = c >> 3, cc = (c & 7) * 8;
    *(uint4*)&Ksh[row * KPAD + cc] = *(const uint4*)&qkv[baseK + (size_t)row * 1536 + cc];
  }
  __syncthreads();

  const int qt0 = q0 + wave * 16;                 // wave's first query
  // Q A-frags direct from global: Q[m=l15][k=quad*8+j], d-chunks 0/1
  const size_t baseQ = ((size_t)(b * TT + qt0 + l15)) * 1536 + h * 64;
  const bf16x8 aq0 = *(const bf16x8*)&qkv[baseQ + quad * 8];
  const bf16x8 aq1 = *(const bf16x8*)&qkv[baseQ + 32 + quad * 8];

  f32x4 o0 = {}, o1 = {}, o2 = {}, o3 = {};
  float mr[4] = {-1e30f, -1e30f, -1e30f, -1e30f};
  float lr[4] = {0.f, 0.f, 0.f, 0.f};

  const int klo = (qt0 > (WWIN - 1)) ? (qt0 - (WWIN - 1)) : 0;
  const int c_lo = (klo - j0) >> 5;
  const int c_hi = (qt0 + 15 - j0) >> 5;
  __hip_bfloat16* Pw = &Psh[wave * 16 * PPAD];
  const short* qs = (const short*)qkv;

  for (int c = c_lo; c <= c_hi; ++c) {
    const int krel = c * 32;
    // K B-frags from LDS
    bf16x8 bk00 = *(const bf16x8*)&Ksh[(krel + l15) * KPAD + quad * 8];
    bf16x8 bk01 = *(const bf16x8*)&Ksh[(krel + l15) * KPAD + 32 + quad * 8];
    bf16x8 bk10 = *(const bf16x8*)&Ksh[(krel + 16 + l15) * KPAD + quad * 8];
    bf16x8 bk11 = *(const bf16x8*)&Ksh[(krel + 16 + l15) * KPAD + 32 + quad * 8];
    f32x4 z = {};
    f32x4 s0 = __builtin_amdgcn_mfma_f32_16x16x32_bf16(aq0, bk00, z, 0, 0, 0);
    s0 = __builtin_amdgcn_mfma_f32_16x16x32_bf16(aq1, bk01, s0, 0, 0, 0);
    f32x4 s1 = __builtin_amdgcn_mfma_f32_16x16x32_bf16(aq0, bk10, z, 0, 0, 0);
    s1 = __builtin_amdgcn_mfma_f32_16x16x32_bf16(aq1, bk11, s1, 0, 0, 0);

    const int jj0 = j0 + krel + l15;
    const int jj1 = jj0 + 16;
#pragma unroll
    for (int r = 0; r < 4; ++r) {
      const int qrow = qt0 + quad * 4 + r;
      const bool ok0 = (jj0 <= qrow) && ((qrow - jj0) < WWIN);
      const bool ok1 = (jj1 <= qrow) && ((qrow - jj1) < WWIN);
      float v0 = ok0 ? s0[r] * 0.125f : -1e30f;
      float v1 = ok1 ? s1[r] * 0.125f : -1e30f;
      float mx = fmaxf(v0, v1);
#pragma unroll
      for (int off = 8; off; off >>= 1) mx = fmaxf(mx, __shfl_xor(mx, off, 16));
      const float mn = fmaxf(mr[r], mx);
      const float alpha = expf(mr[r] - mn);
      const float p0 = ok0 ? expf(v0 - mn) : 0.f;
      const float p1 = ok1 ? expf(v1 - mn) : 0.f;
      float ps = p0 + p1;
#pragma unroll
      for (int off = 8; off; off >>= 1) ps += __shfl_xor(ps, off, 16);
      lr[r] = lr[r] * alpha + ps;
      mr[r] = mn;
      o0[r] *= alpha; o1[r] *= alpha; o2[r] *= alpha; o3[r] *= alpha;
      const int qloc = quad * 4 + r;
      Pw[qloc * PPAD + l15]      = __float2bfloat16(p0);
      Pw[qloc * PPAD + 16 + l15] = __float2bfloat16(p1);
    }
    // wave-local: ensure P writes visible to cross-lane A-frag reads
    asm volatile("s_waitcnt lgkmcnt(0)" ::: "memory");
    __builtin_amdgcn_wave_barrier();
    const bf16x8 pa = *(const bf16x8*)&Pw[l15 * PPAD + quad * 8];

    // V B-frags from global: lane holds V[key0+quad*8+j][t*16+l15]
    const int key0 = j0 + krel;
    size_t voff[8];
#pragma unroll
    for (int j = 0; j < 8; ++j) {
      int rowj = key0 + quad * 8 + j;
      rowj = (rowj > TT - 1) ? (TT - 1) : rowj;   // clamp: P=0 rows must read finite data
      voff[j] = ((size_t)(b * TT + rowj)) * 1536 + 1024 + h * 64 + l15;
    }
#pragma unroll
    for (int t = 0; t < 4; ++t) {
      bf16x8 bv;
#pragma unroll
      for (int j = 0; j < 8; ++j) bv[j] = qs[voff[j] + t * 16];
      if (t == 0)      o0 = __builtin_amdgcn_mfma_f32_16x16x32_bf16(pa, bv, o0, 0, 0, 0);
      else if (t == 1) o1 = __builtin_amdgcn_mfma_f32_16x16x32_bf16(pa, bv, o1, 0, 0, 0);
      else if (t == 2) o2 = __builtin_amdgcn_mfma_f32_16x16x32_bf16(pa, bv, o2, 0, 0, 0);
      else             o3 = __builtin_amdgcn_mfma_f32_16x16x32_bf16(pa, bv, o3, 0, 0, 0);
    }
    __builtin_amdgcn_wave_barrier();
  }

  // epilogue: normalize + write (C-layout: col=d=t*16+l15, row=q=quad*4+r)
#pragma unroll
  for (int r = 0; r < 4; ++r) {
    const float inv = 1.f / lr[r];
    const size_t ob = ((size_t)(b * TT + qt0 + quad * 4 + r)) * DD + h * 64 + l15;
    ao[ob]      = __float2bfloat16(o0[r] * inv);
    ao[ob + 16] = __float2bfloat16(o1[r] * inv);
    ao[ob + 32] = __float2bfloat16(o2[r] * inv);
    ao[ob + 48] = __float2bfloat16(o3[r] * inv);
  }
}

// ---------- host launch ----------
extern "C" void kernel_launch(void* const* d_in, const int* in_sizes, int n_in,
                              void* d_out, int out_size, void* d_ws, size_t ws_size,
                              hipStream_t stream) {
  float* outF = (float*)d_out;   // fp32 output; doubles as residual x

  int code = 0;
  if (n_in != 19)                      code = 1;
  else if (in_sizes[0]  != 2097152)    code = 2;
  else if (in_sizes[1]  != 1048576)    code = 3;
  else if (in_sizes[9]  != 4194304)    code = 4;
  else if (in_sizes[17] != 512)        code = 5;
  if (code != 0 || ws_size < 23100000ull) {
    float C = code ? (150.f + 15.f * (float)code) : (1000.f + (float)(ws_size >> 20));
    fill_const<<<8192, 256, 0, stream>>>(outF, C, NOUT);
    return;
  }

  const float* tokens = (const float*)d_in[0];
  const float* Wq  = (const float*)d_in[1];
  const float* Wk  = (const float*)d_in[2];
  const float* Wv  = (const float*)d_in[3];
  const float* Wo  = (const float*)d_in[4];
  const float* bq  = (const float*)d_in[5];
  const float* bk  = (const float*)d_in[6];
  const float* bv  = (const float*)d_in[7];
  const float* bo  = (const float*)d_in[8];
  const float* W1  = (const float*)d_in[9];
  const float* b1  = (const float*)d_in[10];
  const float* W2  = (const float*)d_in[11];
  const float* b2  = (const float*)d_in[12];
  const float* g1  = (const float*)d_in[13];
  const float* be1 = (const float*)d_in[14];
  const float* g2  = (const float*)d_in[15];
  const float* be2 = (const float*)d_in[16];
  const float* gf  = (const float*)d_in[17];
  const float* bf  = (const float*)d_in[18];

  char* ws = (char*)d_ws;
  __hip_bfloat16* xn   = (__hip_bfloat16*)(ws + 0);          //  4,194,304
  __hip_bfloat16* qkv  = (__hip_bfloat16*)(ws + 4194304);    // 12,582,912
  __hip_bfloat16* ao   = (__hip_bfloat16*)(ws + 16777216);   //  4,194,304
  __hip_bfloat16* hbuf = (__hip_bfloat16*)(ws + 4194304);    // aliases qkv+ao
  __hip_bfloat16* wT   = (__hip_bfloat16*)(ws + 20971520);   //  2,097,152
  float* bqkvc         = (float*)(ws + 23068672);            //  24,576 -> 23,093,248
  float* x             = outF;

  copy_f32<<<8192, 256, 0, stream>>>(tokens, x, NOUT);
  bqkv_cat<<<24, 256, 0, stream>>>(bq, bk, bv, bqkvc);

  for (int l = 0; l < LL; ++l) {
    ln_kernel<<<1024, 256, 0, stream>>>(x, g1 + l * 512, be1 + l * 512, xn);
    transpose_wb<<<dim3(16, 16), 256, 0, stream>>>(Wq + (size_t)l * 262144, wT,          512, 512);
    transpose_wb<<<dim3(16, 16), 256, 0, stream>>>(Wk + (size_t)l * 262144, wT + 262144, 512, 512);
    transpose_wb<<<dim3(16, 16), 256, 0, stream>>>(Wv + (size_t)l * 262144, wT + 524288, 512, 512);
    gemm_bt<EPI_BF16><<<dim3(12, 32), 256, 0, stream>>>(
        xn, wT, bqkvc + l * 1536, qkv, nullptr, MM, 1536, 512, 1536, 0);
    rope_kernel<<<4096, 256, 0, stream>>>(qkv);
    attn_mfma<<<dim3(32, 16), 256, 0, stream>>>(qkv, ao);
    transpose_wb<<<dim3(16, 16), 256, 0, stream>>>(Wo + (size_t)l * 262144, wT, 512, 512);
    gemm_bt<EPI_ADDF32><<<dim3(4, 32), 256, 0, stream>>>(
        ao, wT, bo + l * 512, nullptr, x, MM, 512, 512, 512, 0);
    ln_kernel<<<1024, 256, 0, stream>>>(x, g2 + l * 512, be2 + l * 512, xn);
    transpose_wb<<<dim3(64, 16), 256, 0, stream>>>(W1 + (size_t)l * 1048576, wT, 512, 2048);
    gemm_bt<EPI_GELU><<<dim3(16, 32), 256, 0, stream>>>(
        xn, wT, b1 + l * 2048, hbuf, nullptr, MM, 2048, 512, 2048, 0);
    transpose_wb<<<dim3(16, 64), 256, 0, stream>>>(W2 + (size_t)l * 1048576, wT, 2048, 512);
    gemm_bt<EPI_ADDF32><<<dim3(4, 32), 256, 0, stream>>>(
        hbuf, wT, b2 + l * 512, nullptr, x, MM, 512, 2048, 512, 0);
  }
  ln_f32out<<<1024, 256, 0, stream>>>(x, gf, bf, outF);
}

// Round 10
// 691.581 us; speedup vs baseline: 7.0240x; 1.1931x over previous
//
#include <hip/hip_runtime.h>
#include <hip/hip_bf16.h>

#define BQ 2
#define TT 2048
#define DD 512
#define HH 8
#define LL 4
#define DFFN 2048
#define WWIN 256
#define DHD 64
#define MM (BQ*TT)   // 4096 token rows
#define NOUT (MM*DD)

typedef __attribute__((ext_vector_type(8))) short bf16x8;
typedef __attribute__((ext_vector_type(4))) float f32x4;

// ---------- helpers ----------
__device__ __forceinline__ void lds_load16(const void* g, void* l) {
  __builtin_amdgcn_global_load_lds((const __attribute__((address_space(1))) void*)g,
                                   (__attribute__((address_space(3))) void*)l,
                                   16, 0, 0);
}

// ---------- diagnostic fill ----------
__global__ __launch_bounds__(256) void fill_const(float* __restrict__ out, float C, int n) {
  int i = blockIdx.x * 256 + threadIdx.x;
  if (i < n) out[i] = C;
}

// ---------- tokens -> fp32 residual ----------
__global__ __launch_bounds__(256) void copy_f32(const float* __restrict__ in,
                                                float* __restrict__ out, int n) {
  int i = blockIdx.x * 256 + threadIdx.x;
  if (i < n) out[i] = in[i];
}

// ---------- concat qkv biases ----------
__global__ __launch_bounds__(256) void bqkv_cat(const float* __restrict__ bq,
                                                const float* __restrict__ bk,
                                                const float* __restrict__ bv,
                                                float* __restrict__ o) {
  int idx = blockIdx.x * 256 + threadIdx.x;
  if (idx >= LL * 1536) return;
  int l = idx / 1536, n = idx % 1536;
  float v;
  if (n < 512)       v = bq[l * 512 + n];
  else if (n < 1024) v = bk[l * 512 + n - 512];
  else               v = bv[l * 512 + n - 1024];
  o[idx] = v;
}

// ---------- fused per-layer weight transpose: fp32 (K,N) -> bf16 (N,K) ----------
// one dispatch handles Wq,Wk,Wv (->wqkvT rows 0/512/1024), Wo, W1, W2.
// blocks: [0,768) qkv, [768,1024) Wo, [1024,2048) W1, [2048,3072) W2.
__global__ __launch_bounds__(256) void transpose_layer(const float* __restrict__ Wq,
                                                       const float* __restrict__ Wk,
                                                       const float* __restrict__ Wv,
                                                       const float* __restrict__ Wo,
                                                       const float* __restrict__ W1,
                                                       const float* __restrict__ W2,
                                                       __hip_bfloat16* __restrict__ wqkvT,
                                                       __hip_bfloat16* __restrict__ woT,
                                                       __hip_bfloat16* __restrict__ w1T,
                                                       __hip_bfloat16* __restrict__ w2T) {
  __shared__ float tile[32][33];
  const int b = blockIdx.x;
  const float* src;
  __hip_bfloat16* dst;
  int K, N, t;
  if (b < 768) {
    int which = b >> 8; t = b & 255;
    src = (which == 0) ? Wq : (which == 1) ? Wk : Wv;
    dst = wqkvT + which * 262144;   // 512 rows x 512 K per section
    K = 512; N = 512;
  } else if (b < 1024) {
    t = b - 768;  src = Wo; dst = woT; K = 512; N = 512;
  } else if (b < 2048) {
    t = b - 1024; src = W1; dst = w1T; K = 512; N = 2048;
  } else {
    t = b - 2048; src = W2; dst = w2T; K = 2048; N = 512;
  }
  const int tilesN = N >> 5;
  const int n0 = (t % tilesN) * 32, k0 = (t / tilesN) * 32;
  const int tx = threadIdx.x & 31, ty = threadIdx.x >> 5;
#pragma unroll
  for (int r = 0; r < 32; r += 8)
    tile[ty + r][tx] = src[(size_t)(k0 + ty + r) * N + n0 + tx];
  __syncthreads();
#pragma unroll
  for (int r = 0; r < 32; r += 8)
    dst[(size_t)(n0 + ty + r) * K + k0 + tx] = __float2bfloat16(tile[tx][ty + r]);
}

// ---------- LayerNorm: fp32 -> bf16 ----------
__global__ __launch_bounds__(256) void ln_kernel(const float* __restrict__ x,
                                                 const float* __restrict__ g,
                                                 const float* __restrict__ b,
                                                 __hip_bfloat16* __restrict__ out) {
  const int wave = threadIdx.x >> 6, lane = threadIdx.x & 63;
  const int row = blockIdx.x * 4 + wave;
  const float* xr = x + (size_t)row * DD;
  float v[8];
  float s = 0.f;
#pragma unroll
  for (int i = 0; i < 8; ++i) { v[i] = xr[lane + i * 64]; s += v[i]; }
#pragma unroll
  for (int off = 32; off; off >>= 1) s += __shfl_xor(s, off);
  float mu = s * (1.f / DD);
  float qs = 0.f;
#pragma unroll
  for (int i = 0; i < 8; ++i) { float d = v[i] - mu; qs += d * d; }
#pragma unroll
  for (int off = 32; off; off >>= 1) qs += __shfl_xor(qs, off);
  float rstd = rsqrtf(qs * (1.f / DD) + 1e-5f);
#pragma unroll
  for (int i = 0; i < 8; ++i) {
    int c = lane + i * 64;
    out[(size_t)row * DD + c] = __float2bfloat16((v[i] - mu) * rstd * g[c] + b[c]);
  }
}

// ---------- final LayerNorm: fp32 -> fp32 ----------
__global__ __launch_bounds__(256) void ln_f32out(const float* __restrict__ x,
                                                 const float* __restrict__ g,
                                                 const float* __restrict__ b,
                                                 float* __restrict__ out) {
  const int wave = threadIdx.x >> 6, lane = threadIdx.x & 63;
  const int row = blockIdx.x * 4 + wave;
  const float* xr = x + (size_t)row * DD;
  float v[8];
  float s = 0.f;
#pragma unroll
  for (int i = 0; i < 8; ++i) { v[i] = xr[lane + i * 64]; s += v[i]; }
#pragma unroll
  for (int off = 32; off; off >>= 1) s += __shfl_xor(s, off);
  float mu = s * (1.f / DD);
  float qs = 0.f;
#pragma unroll
  for (int i = 0; i < 8; ++i) { float d = v[i] - mu; qs += d * d; }
#pragma unroll
  for (int off = 32; off; off >>= 1) qs += __shfl_xor(qs, off);
  float rstd = rsqrtf(qs * (1.f / DD) + 1e-5f);
#pragma unroll
  for (int i = 0; i < 8; ++i) {
    int c = lane + i * 64;
    out[(size_t)row * DD + c] = (v[i] - mu) * rstd * g[c] + b[c];
  }
}

// ---------- RoPE in-place ----------
__global__ __launch_bounds__(256) void rope_kernel(__hip_bfloat16* __restrict__ qkv) {
  int idx = blockIdx.x * 256 + threadIdx.x;
  int i = idx & 31;
  int h = (idx >> 5) & 7;
  int t = (idx >> 8) & 2047;
  int b = idx >> 19;
  size_t base = ((size_t)(b * TT + t)) * 1536 + h * 64;
  float freq = powf(10000.f, -(float)i * (1.f / 32.f));
  float ang = (float)t * freq;
  float c = cosf(ang), s = sinf(ang);
  float a0 = __bfloat162float(qkv[base + i]);
  float a1 = __bfloat162float(qkv[base + i + 32]);
  qkv[base + i]      = __float2bfloat16(a0 * c - a1 * s);
  qkv[base + i + 32] = __float2bfloat16(a1 * c + a0 * s);
  base += 512;
  a0 = __bfloat162float(qkv[base + i]);
  a1 = __bfloat162float(qkv[base + i + 32]);
  qkv[base + i]      = __float2bfloat16(a0 * c - a1 * s);
  qkv[base + i + 32] = __float2bfloat16(a1 * c + a0 * s);
}

// ---------- MFMA GEMM, double-buffered glds K-loop ----------
// Per half-iter: barrier drains previous buffer's glds; issue glds for the
// OTHER buffer; compute current. Load latency overlaps the MFMA phase —
// the win at 1-2 blocks/CU where no implicit wave overlap exists.
enum { EPI_BF16 = 0, EPI_GELU = 1, EPI_ADDF32 = 2 };

template <int EPI>
__global__ __launch_bounds__(256, 1) void gemm_bt(const __hip_bfloat16* __restrict__ A,
                                                  const __hip_bfloat16* __restrict__ BT,
                                                  const float* __restrict__ bias,
                                                  __hip_bfloat16* __restrict__ Obf,
                                                  float* __restrict__ Of,
                                                  int M, int N, int K,
                                                  int ostride, int ooff) {
  __shared__ __align__(16) __hip_bfloat16 Ash0[128 * 32];
  __shared__ __align__(16) __hip_bfloat16 Ash1[128 * 32];
  __shared__ __align__(16) __hip_bfloat16 Bsh0[128 * 32];
  __shared__ __align__(16) __hip_bfloat16 Bsh1[128 * 32];
  const int tid = threadIdx.x;
  const int wave = tid >> 6;
  const int lane = tid & 63;
  const int m0 = blockIdx.y * 128;
  const int n0 = blockIdx.x * 128;
  const int wm = (wave >> 1) * 64;
  const int wn = (wave & 1) * 64;
  const int l15 = lane & 15;
  const int quad = lane >> 4;

  f32x4 acc[4][4] = {};

  const int r0 = tid >> 2;            // rows 0..63
  const int r1 = r0 + 64;             // rows 64..127
  const int o0 = (tid & 3) * 8;       // k-offset (16B chunks)

  const __hip_bfloat16* Ap0 = A + (size_t)(m0 + r0) * K + o0;
  const __hip_bfloat16* Ap1 = A + (size_t)(m0 + r1) * K + o0;
  const __hip_bfloat16* Bp0 = BT + (size_t)(n0 + r0) * K + o0;
  const __hip_bfloat16* Bp1 = BT + (size_t)(n0 + r1) * K + o0;

  auto stage = [&](__hip_bfloat16* As, __hip_bfloat16* Bs, int k) {
    // wave-uniform LDS base; HW scatters lane*16B
    lds_load16(Ap0 + k, As + wave * 512);
    lds_load16(Ap1 + k, As + 2048 + wave * 512);
    lds_load16(Bp0 + k, Bs + wave * 512);
    lds_load16(Bp1 + k, Bs + 2048 + wave * 512);
  };
  auto compute = [&](const __hip_bfloat16* As, const __hip_bfloat16* Bs) {
    bf16x8 af[4], bfr[4];
#pragma unroll
    for (int i = 0; i < 4; ++i)
      af[i] = *(const bf16x8*)&As[(wm + i * 16 + l15) * 32 + quad * 8];
#pragma unroll
    for (int j = 0; j < 4; ++j)
      bfr[j] = *(const bf16x8*)&Bs[(wn + j * 16 + l15) * 32 + quad * 8];
#pragma unroll
    for (int i = 0; i < 4; ++i)
#pragma unroll
      for (int j = 0; j < 4; ++j)
        acc[i][j] = __builtin_amdgcn_mfma_f32_16x16x32_bf16(af[i], bfr[j], acc[i][j], 0, 0, 0);
  };

  stage(Ash0, Bsh0, 0);                       // prologue
  for (int k0 = 0; k0 < K; k0 += 64) {        // K % 64 == 0 (512, 2048)
    __syncthreads();                          // drains glds -> buf0; prior buf1 reads done
    if (k0 + 32 < K) stage(Ash1, Bsh1, k0 + 32);
    compute(Ash0, Bsh0);
    __syncthreads();                          // drains glds -> buf1; prior buf0 reads done
    if (k0 + 64 < K) stage(Ash0, Bsh0, k0 + 64);
    compute(Ash1, Bsh1);
  }

#pragma unroll
  for (int j = 0; j < 4; ++j) {
    const int col = n0 + wn + j * 16 + l15;
    const float bv = bias[col];
#pragma unroll
    for (int i = 0; i < 4; ++i) {
      const int row = m0 + wm + i * 16 + quad * 4;
#pragma unroll
      for (int r = 0; r < 4; ++r) {
        float v = acc[i][j][r] + bv;
        size_t idx = (size_t)(row + r) * ostride + ooff + col;
        if (EPI == EPI_BF16) {
          Obf[idx] = __float2bfloat16(v);
        } else if (EPI == EPI_GELU) {
          float ge = 0.5f * v * (1.f + erff(v * 0.70710678118654752f));
          Obf[idx] = __float2bfloat16(ge);
        } else {
          Of[idx] += v;
        }
      }
    }
  }
}

// ---------- MFMA flash attention (unchanged from round 9, verified) ----------
__global__ __launch_bounds__(256, 1) void attn_mfma(const __hip_bfloat16* __restrict__ qkv,
                                                    __hip_bfloat16* __restrict__ ao) {
  constexpr int KPAD = 72;
  constexpr int PPAD = 40;
  __shared__ __align__(16) __hip_bfloat16 Ksh[320 * KPAD];
  __shared__ __align__(16) __hip_bfloat16 Psh[4 * 16 * PPAD];
  const int tid = threadIdx.x;
  const int wave = tid >> 6;
  const int lane = tid & 63;
  const int l15 = lane & 15;
  const int quad = lane >> 4;
  const int bh = blockIdx.y;
  const int b = bh >> 3, h = bh & 7;
  const int q0 = blockIdx.x * 64;
  const int j0 = (q0 > (WWIN - 1)) ? (q0 - (WWIN - 1)) : 0;
  const int nk = (q0 + 63) - j0 + 1;              // <= 319

  const size_t baseK = ((size_t)(b * TT + j0)) * 1536 + 512 + h * 64;
  for (int c = tid; c < nk * 8; c += 256) {
    int row = c >> 3, cc = (c & 7) * 8;
    *(uint4*)&Ksh[row * KPAD + cc] = *(const uint4*)&qkv[baseK + (size_t)row * 1536 + cc];
  }
  __syncthreads();

  const int qt0 = q0 + wave * 16;
  const size_t baseQ = ((size_t)(b * TT + qt0 + l15)) * 1536 + h * 64;
  const bf16x8 aq0 = *(const bf16x8*)&qkv[baseQ + quad * 8];
  const bf16x8 aq1 = *(const bf16x8*)&qkv[baseQ + 32 + quad * 8];

  f32x4 o0 = {}, o1 = {}, o2 = {}, o3 = {};
  float mr[4] = {-1e30f, -1e30f, -1e30f, -1e30f};
  float lr[4] = {0.f, 0.f, 0.f, 0.f};

  const int klo = (qt0 > (WWIN - 1)) ? (qt0 - (WWIN - 1)) : 0;
  const int c_lo = (klo - j0) >> 5;
  const int c_hi = (qt0 + 15 - j0) >> 5;
  __hip_bfloat16* Pw = &Psh[wave * 16 * PPAD];
  const short* qs = (const short*)qkv;

  for (int c = c_lo; c <= c_hi; ++c) {
    const int krel = c * 32;
    bf16x8 bk00 = *(const bf16x8*)&Ksh[(krel + l15) * KPAD + quad * 8];
    bf16x8 bk01 = *(const bf16x8*)&Ksh[(krel + l15) * KPAD + 32 + quad * 8];
    bf16x8 bk10 = *(const bf16x8*)&Ksh[(krel + 16 + l15) * KPAD + quad * 8];
    bf16x8 bk11 = *(const bf16x8*)&Ksh[(krel + 16 + l15) * KPAD + 32 + quad * 8];
    f32x4 z = {};
    f32x4 s0 = __builtin_amdgcn_mfma_f32_16x16x32_bf16(aq0, bk00, z, 0, 0, 0);
    s0 = __builtin_amdgcn_mfma_f32_16x16x32_bf16(aq1, bk01, s0, 0, 0, 0);
    f32x4 s1 = __builtin_amdgcn_mfma_f32_16x16x32_bf16(aq0, bk10, z, 0, 0, 0);
    s1 = __builtin_amdgcn_mfma_f32_16x16x32_bf16(aq1, bk11, s1, 0, 0, 0);

    const int jj0 = j0 + krel + l15;
    const int jj1 = jj0 + 16;
#pragma unroll
    for (int r = 0; r < 4; ++r) {
      const int qrow = qt0 + quad * 4 + r;
      const bool ok0 = (jj0 <= qrow) && ((qrow - jj0) < WWIN);
      const bool ok1 = (jj1 <= qrow) && ((qrow - jj1) < WWIN);
      float v0 = ok0 ? s0[r] * 0.125f : -1e30f;
      float v1 = ok1 ? s1[r] * 0.125f : -1e30f;
      float mx = fmaxf(v0, v1);
#pragma unroll
      for (int off = 8; off; off >>= 1) mx = fmaxf(mx, __shfl_xor(mx, off, 16));
      const float mn = fmaxf(mr[r], mx);
      const float alpha = expf(mr[r] - mn);
      const float p0 = ok0 ? expf(v0 - mn) : 0.f;
      const float p1 = ok1 ? expf(v1 - mn) : 0.f;
      float ps = p0 + p1;
#pragma unroll
      for (int off = 8; off; off >>= 1) ps += __shfl_xor(ps, off, 16);
      lr[r] = lr[r] * alpha + ps;
      mr[r] = mn;
      o0[r] *= alpha; o1[r] *= alpha; o2[r] *= alpha; o3[r] *= alpha;
      const int qloc = quad * 4 + r;
      Pw[qloc * PPAD + l15]      = __float2bfloat16(p0);
      Pw[qloc * PPAD + 16 + l15] = __float2bfloat16(p1);
    }
    asm volatile("s_waitcnt lgkmcnt(0)" ::: "memory");
    __builtin_amdgcn_wave_barrier();
    const bf16x8 pa = *(const bf16x8*)&Pw[l15 * PPAD + quad * 8];

    const int key0 = j0 + krel;
    size_t voff[8];
#pragma unroll
    for (int j = 0; j < 8; ++j) {
      int rowj = key0 + quad * 8 + j;
      rowj = (rowj > TT - 1) ? (TT - 1) : rowj;
      voff[j] = ((size_t)(b * TT + rowj)) * 1536 + 1024 + h * 64 + l15;
    }
#pragma unroll
    for (int t = 0; t < 4; ++t) {
      bf16x8 bv;
#pragma unroll
      for (int j = 0; j < 8; ++j) bv[j] = qs[voff[j] + t * 16];
      if (t == 0)      o0 = __builtin_amdgcn_mfma_f32_16x16x32_bf16(pa, bv, o0, 0, 0, 0);
      else if (t == 1) o1 = __builtin_amdgcn_mfma_f32_16x16x32_bf16(pa, bv, o1, 0, 0, 0);
      else if (t == 2) o2 = __builtin_amdgcn_mfma_f32_16x16x32_bf16(pa, bv, o2, 0, 0, 0);
      else             o3 = __builtin_amdgcn_mfma_f32_16x16x32_bf16(pa, bv, o3, 0, 0, 0);
    }
    __builtin_amdgcn_wave_barrier();
  }

#pragma unroll
  for (int r = 0; r < 4; ++r) {
    const float inv = 1.f / lr[r];
    const size_t ob = ((size_t)(b * TT + qt0 + quad * 4 + r)) * DD + h * 64 + l15;
    ao[ob]      = __float2bfloat16(o0[r] * inv);
    ao[ob + 16] = __float2bfloat16(o1[r] * inv);
    ao[ob + 32] = __float2bfloat16(o2[r] * inv);
    ao[ob + 48] = __float2bfloat16(o3[r] * inv);
  }
}

// ---------- host launch ----------
extern "C" void kernel_launch(void* const* d_in, const int* in_sizes, int n_in,
                              void* d_out, int out_size, void* d_ws, size_t ws_size,
                              hipStream_t stream) {
  float* outF = (float*)d_out;   // fp32 output; doubles as residual x

  int code = 0;
  if (n_in != 19)                      code = 1;
  else if (in_sizes[0]  != 2097152)    code = 2;
  else if (in_sizes[1]  != 1048576)    code = 3;
  else if (in_sizes[9]  != 4194304)    code = 4;
  else if (in_sizes[17] != 512)        code = 5;
  if (code != 0 || ws_size < 27287552ull) {
    float C = code ? (150.f + 15.f * (float)code) : (1000.f + (float)(ws_size >> 20));
    fill_const<<<8192, 256, 0, stream>>>(outF, C, NOUT);
    return;
  }

  const float* tokens = (const float*)d_in[0];
  const float* Wq  = (const float*)d_in[1];
  const float* Wk  = (const float*)d_in[2];
  const float* Wv  = (const float*)d_in[3];
  const float* Wo  = (const float*)d_in[4];
  const float* bq  = (const float*)d_in[5];
  const float* bk  = (const float*)d_in[6];
  const float* bv  = (const float*)d_in[7];
  const float* bo  = (const float*)d_in[8];
  const float* W1  = (const float*)d_in[9];
  const float* b1  = (const float*)d_in[10];
  const float* W2  = (const float*)d_in[11];
  const float* b2  = (const float*)d_in[12];
  const float* g1  = (const float*)d_in[13];
  const float* be1 = (const float*)d_in[14];
  const float* g2  = (const float*)d_in[15];
  const float* be2 = (const float*)d_in[16];
  const float* gf  = (const float*)d_in[17];
  const float* bf  = (const float*)d_in[18];

  // ws layout — 27,287,552 B total.
  //   [0, 4.19M)      xn / ao (aliased: xn dead when attn writes ao)
  //   [4.19M, 16.78M) qkv; hbuf = [4.19M, 20.97M) (qkv+tail; both dead at FFN)
  //   [20.97M, ...)   wqkvT | woT | w1T | w2T | bqkvc
  char* ws = (char*)d_ws;
  __hip_bfloat16* xnao  = (__hip_bfloat16*)(ws + 0);          //  4,194,304
  __hip_bfloat16* qkv   = (__hip_bfloat16*)(ws + 4194304);    // 12,582,912
  __hip_bfloat16* hbuf  = (__hip_bfloat16*)(ws + 4194304);    // 16,777,216 span
  __hip_bfloat16* wqkvT = (__hip_bfloat16*)(ws + 20971520);   //  1,572,864
  __hip_bfloat16* woT   = (__hip_bfloat16*)(ws + 22544384);   //    524,288
  __hip_bfloat16* w1T   = (__hip_bfloat16*)(ws + 23068672);   //  2,097,152
  __hip_bfloat16* w2T   = (__hip_bfloat16*)(ws + 25165824);   //  2,097,152
  float* bqkvc          = (float*)(ws + 27262976);            //     24,576
  __hip_bfloat16* xn = xnao;
  __hip_bfloat16* ao = xnao;
  float* x = outF;

  copy_f32<<<8192, 256, 0, stream>>>(tokens, x, NOUT);
  bqkv_cat<<<24, 256, 0, stream>>>(bq, bk, bv, bqkvc);

  for (int l = 0; l < LL; ++l) {
    transpose_layer<<<3072, 256, 0, stream>>>(
        Wq + (size_t)l * 262144, Wk + (size_t)l * 262144, Wv + (size_t)l * 262144,
        Wo + (size_t)l * 262144, W1 + (size_t)l * 1048576, W2 + (size_t)l * 1048576,
        wqkvT, woT, w1T, w2T);
    ln_kernel<<<1024, 256, 0, stream>>>(x, g1 + l * 512, be1 + l * 512, xn);
    gemm_bt<EPI_BF16><<<dim3(12, 32), 256, 0, stream>>>(
        xn, wqkvT, bqkvc + l * 1536, qkv, nullptr, MM, 1536, 512, 1536, 0);
    rope_kernel<<<4096, 256, 0, stream>>>(qkv);
    attn_mfma<<<dim3(32, 16), 256, 0, stream>>>(qkv, ao);
    gemm_bt<EPI_ADDF32><<<dim3(4, 32), 256, 0, stream>>>(
        ao, woT, bo + l * 512, nullptr, x, MM, 512, 512, 512, 0);
    ln_kernel<<<1024, 256, 0, stream>>>(x, g2 + l * 512, be2 + l * 512, xn);
    gemm_bt<EPI_GELU><<<dim3(16, 32), 256, 0, stream>>>(
        xn, w1T, b1 + l * 2048, hbuf, nullptr, MM, 2048, 512, 2048, 0);
    gemm_bt<EPI_ADDF32><<<dim3(4, 32), 256, 0, stream>>>(
        hbuf, w2T, b2 + l * 512, nullptr, x, MM, 512, 2048, 512, 0);
  }
  ln_f32out<<<1024, 256, 0, stream>>>(x, gf, bf, outF);
}

// Round 11
// 631.505 us; speedup vs baseline: 7.6922x; 1.0951x over previous
//
#include <hip/hip_runtime.h>
#include <hip/hip_bf16.h>

#define BQ 2
#define TT 2048
#define DD 512
#define HH 8
#define LL 4
#define DFFN 2048
#define WWIN 256
#define DHD 64
#define MM (BQ*TT)   // 4096 token rows
#define NOUT (MM*DD)

typedef __attribute__((ext_vector_type(8))) short bf16x8;
typedef __attribute__((ext_vector_type(4))) float f32x4;

// ---------- helpers ----------
__device__ __forceinline__ void lds_load16(const void* g, void* l) {
  __builtin_amdgcn_global_load_lds((const __attribute__((address_space(1))) void*)g,
                                   (__attribute__((address_space(3))) void*)l,
                                   16, 0, 0);
}

// ---------- diagnostic fill ----------
__global__ __launch_bounds__(256) void fill_const(float* __restrict__ out, float C, int n) {
  int i = blockIdx.x * 256 + threadIdx.x;
  if (i < n) out[i] = C;
}

// ---------- tokens -> fp32 residual ----------
__global__ __launch_bounds__(256) void copy_f32(const float* __restrict__ in,
                                                float* __restrict__ out, int n) {
  int i = blockIdx.x * 256 + threadIdx.x;
  if (i < n) out[i] = in[i];
}

// ---------- concat qkv biases ----------
__global__ __launch_bounds__(256) void bqkv_cat(const float* __restrict__ bq,
                                                const float* __restrict__ bk,
                                                const float* __restrict__ bv,
                                                float* __restrict__ o) {
  int idx = blockIdx.x * 256 + threadIdx.x;
  if (idx >= LL * 1536) return;
  int l = idx / 1536, n = idx % 1536;
  float v;
  if (n < 512)       v = bq[l * 512 + n];
  else if (n < 1024) v = bk[l * 512 + n - 512];
  else               v = bv[l * 512 + n - 1024];
  o[idx] = v;
}

// ---------- fused per-layer weight transpose: fp32 (K,N) -> bf16 (N,K) ----------
__global__ __launch_bounds__(256) void transpose_layer(const float* __restrict__ Wq,
                                                       const float* __restrict__ Wk,
                                                       const float* __restrict__ Wv,
                                                       const float* __restrict__ Wo,
                                                       const float* __restrict__ W1,
                                                       const float* __restrict__ W2,
                                                       __hip_bfloat16* __restrict__ wqkvT,
                                                       __hip_bfloat16* __restrict__ woT,
                                                       __hip_bfloat16* __restrict__ w1T,
                                                       __hip_bfloat16* __restrict__ w2T) {
  __shared__ float tile[32][33];
  const int b = blockIdx.x;
  const float* src;
  __hip_bfloat16* dst;
  int K, N, t;
  if (b < 768) {
    int which = b >> 8; t = b & 255;
    src = (which == 0) ? Wq : (which == 1) ? Wk : Wv;
    dst = wqkvT + which * 262144;
    K = 512; N = 512;
  } else if (b < 1024) {
    t = b - 768;  src = Wo; dst = woT; K = 512; N = 512;
  } else if (b < 2048) {
    t = b - 1024; src = W1; dst = w1T; K = 512; N = 2048;
  } else {
    t = b - 2048; src = W2; dst = w2T; K = 2048; N = 512;
  }
  const int tilesN = N >> 5;
  const int n0 = (t % tilesN) * 32, k0 = (t / tilesN) * 32;
  const int tx = threadIdx.x & 31, ty = threadIdx.x >> 5;
#pragma unroll
  for (int r = 0; r < 32; r += 8)
    tile[ty + r][tx] = src[(size_t)(k0 + ty + r) * N + n0 + tx];
  __syncthreads();
#pragma unroll
  for (int r = 0; r < 32; r += 8)
    dst[(size_t)(n0 + ty + r) * K + k0 + tx] = __float2bfloat16(tile[tx][ty + r]);
}

// ---------- LayerNorm: fp32 -> bf16 ----------
__global__ __launch_bounds__(256) void ln_kernel(const float* __restrict__ x,
                                                 const float* __restrict__ g,
                                                 const float* __restrict__ b,
                                                 __hip_bfloat16* __restrict__ out) {
  const int wave = threadIdx.x >> 6, lane = threadIdx.x & 63;
  const int row = blockIdx.x * 4 + wave;
  const float* xr = x + (size_t)row * DD;
  float v[8];
  float s = 0.f;
#pragma unroll
  for (int i = 0; i < 8; ++i) { v[i] = xr[lane + i * 64]; s += v[i]; }
#pragma unroll
  for (int off = 32; off; off >>= 1) s += __shfl_xor(s, off);
  float mu = s * (1.f / DD);
  float qs = 0.f;
#pragma unroll
  for (int i = 0; i < 8; ++i) { float d = v[i] - mu; qs += d * d; }
#pragma unroll
  for (int off = 32; off; off >>= 1) qs += __shfl_xor(qs, off);
  float rstd = rsqrtf(qs * (1.f / DD) + 1e-5f);
#pragma unroll
  for (int i = 0; i < 8; ++i) {
    int c = lane + i * 64;
    out[(size_t)row * DD + c] = __float2bfloat16((v[i] - mu) * rstd * g[c] + b[c]);
  }
}

// ---------- final LayerNorm: fp32 -> fp32 ----------
__global__ __launch_bounds__(256) void ln_f32out(const float* __restrict__ x,
                                                 const float* __restrict__ g,
                                                 const float* __restrict__ b,
                                                 float* __restrict__ out) {
  const int wave = threadIdx.x >> 6, lane = threadIdx.x & 63;
  const int row = blockIdx.x * 4 + wave;
  const float* xr = x + (size_t)row * DD;
  float v[8];
  float s = 0.f;
#pragma unroll
  for (int i = 0; i < 8; ++i) { v[i] = xr[lane + i * 64]; s += v[i]; }
#pragma unroll
  for (int off = 32; off; off >>= 1) s += __shfl_xor(s, off);
  float mu = s * (1.f / DD);
  float qs = 0.f;
#pragma unroll
  for (int i = 0; i < 8; ++i) { float d = v[i] - mu; qs += d * d; }
#pragma unroll
  for (int off = 32; off; off >>= 1) qs += __shfl_xor(qs, off);
  float rstd = rsqrtf(qs * (1.f / DD) + 1e-5f);
#pragma unroll
  for (int i = 0; i < 8; ++i) {
    int c = lane + i * 64;
    out[(size_t)row * DD + c] = (v[i] - mu) * rstd * g[c] + b[c];
  }
}

// ---------- MFMA GEMM: dbuf glds K-loop + split-K + optional fused RoPE ----------
// Split-K: blockIdx.z picks slice [z*KS, (z+1)*KS); EPI_ADDF32 uses atomicAdd
// (order-independent fp32 accumulation into residual); bias added by z==0 only.
// ROPE (QKV only): pair (d, d+32) of a head lives in acc[i][j]/acc[i][j+2]
// of the SAME lane (head-dim = j*16+l15); rotate before the bf16 store.
enum { EPI_BF16 = 0, EPI_GELU = 1, EPI_ADDF32 = 2 };

template <int EPI, bool ROPE>
__global__ __launch_bounds__(256, 1) void gemm_bt(const __hip_bfloat16* __restrict__ A,
                                                  const __hip_bfloat16* __restrict__ BT,
                                                  const float* __restrict__ bias,
                                                  __hip_bfloat16* __restrict__ Obf,
                                                  float* __restrict__ Of,
                                                  int M, int N, int K, int KS,
                                                  int ostride, int ooff) {
  __shared__ __align__(16) __hip_bfloat16 Ash0[128 * 32];
  __shared__ __align__(16) __hip_bfloat16 Ash1[128 * 32];
  __shared__ __align__(16) __hip_bfloat16 Bsh0[128 * 32];
  __shared__ __align__(16) __hip_bfloat16 Bsh1[128 * 32];
  const int tid = threadIdx.x;
  const int wave = tid >> 6;
  const int lane = tid & 63;
  const int m0 = blockIdx.y * 128;
  const int n0 = blockIdx.x * 128;
  const int kbase = blockIdx.z * KS;
  const int wm = (wave >> 1) * 64;
  const int wn = (wave & 1) * 64;
  const int l15 = lane & 15;
  const int quad = lane >> 4;

  f32x4 acc[4][4] = {};

  const int r0 = tid >> 2;
  const int r1 = r0 + 64;
  const int o0 = (tid & 3) * 8;

  const __hip_bfloat16* Ap0 = A + (size_t)(m0 + r0) * K + kbase + o0;
  const __hip_bfloat16* Ap1 = A + (size_t)(m0 + r1) * K + kbase + o0;
  const __hip_bfloat16* Bp0 = BT + (size_t)(n0 + r0) * K + kbase + o0;
  const __hip_bfloat16* Bp1 = BT + (size_t)(n0 + r1) * K + kbase + o0;

  auto stage = [&](__hip_bfloat16* As, __hip_bfloat16* Bs, int k) {
    lds_load16(Ap0 + k, As + wave * 512);
    lds_load16(Ap1 + k, As + 2048 + wave * 512);
    lds_load16(Bp0 + k, Bs + wave * 512);
    lds_load16(Bp1 + k, Bs + 2048 + wave * 512);
  };
  auto compute = [&](const __hip_bfloat16* As, const __hip_bfloat16* Bs) {
    bf16x8 af[4], bfr[4];
#pragma unroll
    for (int i = 0; i < 4; ++i)
      af[i] = *(const bf16x8*)&As[(wm + i * 16 + l15) * 32 + quad * 8];
#pragma unroll
    for (int j = 0; j < 4; ++j)
      bfr[j] = *(const bf16x8*)&Bs[(wn + j * 16 + l15) * 32 + quad * 8];
#pragma unroll
    for (int i = 0; i < 4; ++i)
#pragma unroll
      for (int j = 0; j < 4; ++j)
        acc[i][j] = __builtin_amdgcn_mfma_f32_16x16x32_bf16(af[i], bfr[j], acc[i][j], 0, 0, 0);
  };

  stage(Ash0, Bsh0, 0);
  for (int k0 = 0; k0 < KS; k0 += 64) {        // KS % 64 == 0
    __syncthreads();
    if (k0 + 32 < KS) stage(Ash1, Bsh1, k0 + 32);
    compute(Ash0, Bsh0);
    __syncthreads();
    if (k0 + 64 < KS) stage(Ash0, Bsh0, k0 + 64);
    compute(Ash1, Bsh1);
  }

  if (ROPE && n0 < 1024) {
    // q/k sections: rotate (d, d+32) pairs
#pragma unroll
    for (int j = 0; j < 2; ++j) {
      const int col = n0 + wn + j * 16 + l15;
      const float bv0 = bias[col], bv1 = bias[col + 32];
      const float freq = __powf(10000.f, -(float)(j * 16 + l15) * (1.f / 32.f));
#pragma unroll
      for (int i = 0; i < 4; ++i) {
        const int row = m0 + wm + i * 16 + quad * 4;
#pragma unroll
        for (int r = 0; r < 4; ++r) {
          const int t = (row + r) & 2047;
          float sn, cs;
          __sincosf((float)t * freq, &sn, &cs);
          const float a0 = acc[i][j][r] + bv0;
          const float a1 = acc[i][j + 2][r] + bv1;
          const size_t idx = (size_t)(row + r) * ostride + ooff + col;
          Obf[idx]      = __float2bfloat16(a0 * cs - a1 * sn);
          Obf[idx + 32] = __float2bfloat16(a1 * cs + a0 * sn);
        }
      }
    }
    return;
  }

#pragma unroll
  for (int j = 0; j < 4; ++j) {
    const int col = n0 + wn + j * 16 + l15;
    const float bv = (blockIdx.z == 0) ? bias[col] : 0.f;
#pragma unroll
    for (int i = 0; i < 4; ++i) {
      const int row = m0 + wm + i * 16 + quad * 4;
#pragma unroll
      for (int r = 0; r < 4; ++r) {
        float v = acc[i][j][r] + bv;
        size_t idx = (size_t)(row + r) * ostride + ooff + col;
        if (EPI == EPI_BF16) {
          Obf[idx] = __float2bfloat16(v);
        } else if (EPI == EPI_GELU) {
          float ge = 0.5f * v * (1.f + erff(v * 0.70710678118654752f));
          Obf[idx] = __float2bfloat16(ge);
        } else {
          atomicAdd(&Of[idx], v);   // split-K safe
        }
      }
    }
  }
}

// ---------- MFMA flash attention (verified, unchanged) ----------
__global__ __launch_bounds__(256, 1) void attn_mfma(const __hip_bfloat16* __restrict__ qkv,
                                                    __hip_bfloat16* __restrict__ ao) {
  constexpr int KPAD = 72;
  constexpr int PPAD = 40;
  __shared__ __align__(16) __hip_bfloat16 Ksh[320 * KPAD];
  __shared__ __align__(16) __hip_bfloat16 Psh[4 * 16 * PPAD];
  const int tid = threadIdx.x;
  const int wave = tid >> 6;
  const int lane = tid & 63;
  const int l15 = lane & 15;
  const int quad = lane >> 4;
  const int bh = blockIdx.y;
  const int b = bh >> 3, h = bh & 7;
  const int q0 = blockIdx.x * 64;
  const int j0 = (q0 > (WWIN - 1)) ? (q0 - (WWIN - 1)) : 0;
  const int nk = (q0 + 63) - j0 + 1;

  const size_t baseK = ((size_t)(b * TT + j0)) * 1536 + 512 + h * 64;
  for (int c = tid; c < nk * 8; c += 256) {
    int row = c >> 3, cc = (c & 7) * 8;
    *(uint4*)&Ksh[row * KPAD + cc] = *(const uint4*)&qkv[baseK + (size_t)row * 1536 + cc];
  }
  __syncthreads();

  const int qt0 = q0 + wave * 16;
  const size_t baseQ = ((size_t)(b * TT + qt0 + l15)) * 1536 + h * 64;
  const bf16x8 aq0 = *(const bf16x8*)&qkv[baseQ + quad * 8];
  const bf16x8 aq1 = *(const bf16x8*)&qkv[baseQ + 32 + quad * 8];

  f32x4 o0 = {}, o1 = {}, o2 = {}, o3 = {};
  float mr[4] = {-1e30f, -1e30f, -1e30f, -1e30f};
  float lr[4] = {0.f, 0.f, 0.f, 0.f};

  const int klo = (qt0 > (WWIN - 1)) ? (qt0 - (WWIN - 1)) : 0;
  const int c_lo = (klo - j0) >> 5;
  const int c_hi = (qt0 + 15 - j0) >> 5;
  __hip_bfloat16* Pw = &Psh[wave * 16 * PPAD];
  const short* qs = (const short*)qkv;

  for (int c = c_lo; c <= c_hi; ++c) {
    const int krel = c * 32;
    bf16x8 bk00 = *(const bf16x8*)&Ksh[(krel + l15) * KPAD + quad * 8];
    bf16x8 bk01 = *(const bf16x8*)&Ksh[(krel + l15) * KPAD + 32 + quad * 8];
    bf16x8 bk10 = *(const bf16x8*)&Ksh[(krel + 16 + l15) * KPAD + quad * 8];
    bf16x8 bk11 = *(const bf16x8*)&Ksh[(krel + 16 + l15) * KPAD + 32 + quad * 8];
    f32x4 z = {};
    f32x4 s0 = __builtin_amdgcn_mfma_f32_16x16x32_bf16(aq0, bk00, z, 0, 0, 0);
    s0 = __builtin_amdgcn_mfma_f32_16x16x32_bf16(aq1, bk01, s0, 0, 0, 0);
    f32x4 s1 = __builtin_amdgcn_mfma_f32_16x16x32_bf16(aq0, bk10, z, 0, 0, 0);
    s1 = __builtin_amdgcn_mfma_f32_16x16x32_bf16(aq1, bk11, s1, 0, 0, 0);

    const int jj0 = j0 + krel + l15;
    const int jj1 = jj0 + 16;
#pragma unroll
    for (int r = 0; r < 4; ++r) {
      const int qrow = qt0 + quad * 4 + r;
      const bool ok0 = (jj0 <= qrow) && ((qrow - jj0) < WWIN);
      const bool ok1 = (jj1 <= qrow) && ((qrow - jj1) < WWIN);
      float v0 = ok0 ? s0[r] * 0.125f : -1e30f;
      float v1 = ok1 ? s1[r] * 0.125f : -1e30f;
      float mx = fmaxf(v0, v1);
#pragma unroll
      for (int off = 8; off; off >>= 1) mx = fmaxf(mx, __shfl_xor(mx, off, 16));
      const float mn = fmaxf(mr[r], mx);
      const float alpha = expf(mr[r] - mn);
      const float p0 = ok0 ? expf(v0 - mn) : 0.f;
      const float p1 = ok1 ? expf(v1 - mn) : 0.f;
      float ps = p0 + p1;
#pragma unroll
      for (int off = 8; off; off >>= 1) ps += __shfl_xor(ps, off, 16);
      lr[r] = lr[r] * alpha + ps;
      mr[r] = mn;
      o0[r] *= alpha; o1[r] *= alpha; o2[r] *= alpha; o3[r] *= alpha;
      const int qloc = quad * 4 + r;
      Pw[qloc * PPAD + l15]      = __float2bfloat16(p0);
      Pw[qloc * PPAD + 16 + l15] = __float2bfloat16(p1);
    }
    asm volatile("s_waitcnt lgkmcnt(0)" ::: "memory");
    __builtin_amdgcn_wave_barrier();
    const bf16x8 pa = *(const bf16x8*)&Pw[l15 * PPAD + quad * 8];

    const int key0 = j0 + krel;
    size_t voff[8];
#pragma unroll
    for (int j = 0; j < 8; ++j) {
      int rowj = key0 + quad * 8 + j;
      rowj = (rowj > TT - 1) ? (TT - 1) : rowj;
      voff[j] = ((size_t)(b * TT + rowj)) * 1536 + 1024 + h * 64 + l15;
    }
#pragma unroll
    for (int t = 0; t < 4; ++t) {
      bf16x8 bv;
#pragma unroll
      for (int j = 0; j < 8; ++j) bv[j] = qs[voff[j] + t * 16];
      if (t == 0)      o0 = __builtin_amdgcn_mfma_f32_16x16x32_bf16(pa, bv, o0, 0, 0, 0);
      else if (t == 1) o1 = __builtin_amdgcn_mfma_f32_16x16x32_bf16(pa, bv, o1, 0, 0, 0);
      else if (t == 2) o2 = __builtin_amdgcn_mfma_f32_16x16x32_bf16(pa, bv, o2, 0, 0, 0);
      else             o3 = __builtin_amdgcn_mfma_f32_16x16x32_bf16(pa, bv, o3, 0, 0, 0);
    }
    __builtin_amdgcn_wave_barrier();
  }

#pragma unroll
  for (int r = 0; r < 4; ++r) {
    const float inv = 1.f / lr[r];
    const size_t ob = ((size_t)(b * TT + qt0 + quad * 4 + r)) * DD + h * 64 + l15;
    ao[ob]      = __float2bfloat16(o0[r] * inv);
    ao[ob + 16] = __float2bfloat16(o1[r] * inv);
    ao[ob + 32] = __float2bfloat16(o2[r] * inv);
    ao[ob + 48] = __float2bfloat16(o3[r] * inv);
  }
}

// ---------- host launch ----------
extern "C" void kernel_launch(void* const* d_in, const int* in_sizes, int n_in,
                              void* d_out, int out_size, void* d_ws, size_t ws_size,
                              hipStream_t stream) {
  float* outF = (float*)d_out;   // fp32 output; doubles as residual x

  int code = 0;
  if (n_in != 19)                      code = 1;
  else if (in_sizes[0]  != 2097152)    code = 2;
  else if (in_sizes[1]  != 1048576)    code = 3;
  else if (in_sizes[9]  != 4194304)    code = 4;
  else if (in_sizes[17] != 512)        code = 5;
  if (code != 0 || ws_size < 27287552ull) {
    float C = code ? (150.f + 15.f * (float)code) : (1000.f + (float)(ws_size >> 20));
    fill_const<<<8192, 256, 0, stream>>>(outF, C, NOUT);
    return;
  }

  const float* tokens = (const float*)d_in[0];
  const float* Wq  = (const float*)d_in[1];
  const float* Wk  = (const float*)d_in[2];
  const float* Wv  = (const float*)d_in[3];
  const float* Wo  = (const float*)d_in[4];
  const float* bq  = (const float*)d_in[5];
  const float* bk  = (const float*)d_in[6];
  const float* bv  = (const float*)d_in[7];
  const float* bo  = (const float*)d_in[8];
  const float* W1  = (const float*)d_in[9];
  const float* b1  = (const float*)d_in[10];
  const float* W2  = (const float*)d_in[11];
  const float* b2  = (const float*)d_in[12];
  const float* g1  = (const float*)d_in[13];
  const float* be1 = (const float*)d_in[14];
  const float* g2  = (const float*)d_in[15];
  const float* be2 = (const float*)d_in[16];
  const float* gf  = (const float*)d_in[17];
  const float* bf  = (const float*)d_in[18];

  char* ws = (char*)d_ws;
  __hip_bfloat16* xnao  = (__hip_bfloat16*)(ws + 0);          //  4,194,304 (xn/ao aliased)
  __hip_bfloat16* qkv   = (__hip_bfloat16*)(ws + 4194304);    // 12,582,912
  __hip_bfloat16* hbuf  = (__hip_bfloat16*)(ws + 4194304);    // 16,777,216 span
  __hip_bfloat16* wqkvT = (__hip_bfloat16*)(ws + 20971520);   //  1,572,864
  __hip_bfloat16* woT   = (__hip_bfloat16*)(ws + 22544384);   //    524,288
  __hip_bfloat16* w1T   = (__hip_bfloat16*)(ws + 23068672);   //  2,097,152
  __hip_bfloat16* w2T   = (__hip_bfloat16*)(ws + 25165824);   //  2,097,152
  float* bqkvc          = (float*)(ws + 27262976);            //     24,576
  __hip_bfloat16* xn = xnao;
  __hip_bfloat16* ao = xnao;
  float* x = outF;

  copy_f32<<<8192, 256, 0, stream>>>(tokens, x, NOUT);
  bqkv_cat<<<24, 256, 0, stream>>>(bq, bk, bv, bqkvc);

  for (int l = 0; l < LL; ++l) {
    transpose_layer<<<3072, 256, 0, stream>>>(
        Wq + (size_t)l * 262144, Wk + (size_t)l * 262144, Wv + (size_t)l * 262144,
        Wo + (size_t)l * 262144, W1 + (size_t)l * 1048576, W2 + (size_t)l * 1048576,
        wqkvT, woT, w1T, w2T);
    ln_kernel<<<1024, 256, 0, stream>>>(x, g1 + l * 512, be1 + l * 512, xn);
    // QKV + fused RoPE
    gemm_bt<EPI_BF16, true><<<dim3(12, 32), 256, 0, stream>>>(
        xn, wqkvT, bqkvc + l * 1536, qkv, nullptr, MM, 1536, 512, 512, 1536, 0);
    attn_mfma<<<dim3(32, 16), 256, 0, stream>>>(qkv, ao);
    // Wo: split-K x2
    gemm_bt<EPI_ADDF32, false><<<dim3(4, 32, 2), 256, 0, stream>>>(
        ao, woT, bo + l * 512, nullptr, x, MM, 512, 512, 256, 512, 0);
    ln_kernel<<<1024, 256, 0, stream>>>(x, g2 + l * 512, be2 + l * 512, xn);
    gemm_bt<EPI_GELU, false><<<dim3(16, 32), 256, 0, stream>>>(
        xn, w1T, b1 + l * 2048, hbuf, nullptr, MM, 2048, 512, 512, 2048, 0);
    // FFN2: split-K x4
    gemm_bt<EPI_ADDF32, false><<<dim3(4, 32, 4), 256, 0, stream>>>(
        hbuf, w2T, b2 + l * 512, nullptr, x, MM, 512, 2048, 512, 512, 0);
  }
  ln_f32out<<<1024, 256, 0, stream>>>(x, gf, bf, outF);
}